// Round 4
// baseline (1998.642 us; speedup 1.0000x reference)
//
#include <hip/hip_runtime.h>
#include <hip/hip_bf16.h>
#include <hip/hip_cooperative_groups.h>

namespace cg = cooperative_groups;

#define NN 10000
#define NE 640000
#define NF 128
#define NH 128
#define NT 128
#define KA 256   // NF + NH
#define LN_EPS 1e-5f
#define NNT 157  // ceil(NN/64)

typedef __bf16 bf16x8 __attribute__((ext_vector_type(8)));
typedef float floatx4 __attribute__((ext_vector_type(4)));
typedef float nfloat4 __attribute__((ext_vector_type(4)));

__device__ inline unsigned short f2bf(float f) {
    unsigned int u = __float_as_uint(f);
    u += 0x7FFFu + ((u >> 16) & 1u);   // round-to-nearest-even
    return (unsigned short)(u >> 16);
}

__device__ inline bf16x8 load_frag(const unsigned short* p) {
    uint4 u = *(const uint4*)p;
    return __builtin_bit_cast(bf16x8, u);
}

// native casts -> v_cvt_pk_bf16_f32 (RTNE), 2 floats/instr
__device__ inline bf16x8 cvt8(nfloat4 v0, nfloat4 v1) {
    bf16x8 r;
    r[0] = (__bf16)v0.x; r[1] = (__bf16)v0.y; r[2] = (__bf16)v0.z; r[3] = (__bf16)v0.w;
    r[4] = (__bf16)v1.x; r[5] = (__bf16)v1.y; r[6] = (__bf16)v1.z; r[7] = (__bf16)v1.w;
    return r;
}

// wave-local LDS ordering fence (R3-proven correct for own-wave write->read)
__device__ inline void lds_fence() {
    asm volatile("s_waitcnt lgkmcnt(0)" ::: "memory");
}

// ===========================================================================
// FUSED single cooperative kernel: zero+pack+cvt -> hist -> scan -> scatter
// -> edge tiles (persistent, XCD-chunked) -> node tiles.
// LDS union: edge {accbuf f32[64][132] (aliased as Atile bf16[64][264]),
// Ttile bf16[64][136], rows_s[64]} / node {Atile, Ttile} / scan {partials}.
// Total 51456 B -> 3 blocks/CU; grid <= 768 guaranteed co-resident by
// cooperative launch. Edge internals = R0 (best measured), with bf16 x.
// ===========================================================================
__global__ __launch_bounds__(256, 3) void fused_kernel(
    const float* __restrict__ x,
    const int* __restrict__ eidx,
    const float* __restrict__ eattr,
    const float* __restrict__ W1a, const float* __restrict__ b1a,
    const float* __restrict__ g1,  const float* __restrict__ be1,
    const float* __restrict__ W1b, const float* __restrict__ b1b,
    const float* __restrict__ W2a, const float* __restrict__ b2a,
    const float* __restrict__ g2,  const float* __restrict__ be2,
    const float* __restrict__ W2b, const float* __restrict__ b2b,
    float* __restrict__ sums, int* __restrict__ hist, int* __restrict__ cursor,
    int* __restrict__ row_start, int* __restrict__ perm,
    unsigned short* __restrict__ wp1a, unsigned short* __restrict__ wp1b,
    unsigned short* __restrict__ wp2a, unsigned short* __restrict__ wp2b,
    unsigned short* __restrict__ xbf,
    float* __restrict__ out)
{
    cg::grid_group gridg = cg::this_grid();
    __shared__ __align__(16) float smem[12864];          // 51456 B

    const int nb  = gridDim.x;
    const int nth = nb * 256;
    const int tid = blockIdx.x * 256 + threadIdx.x;
    const int* erow = eidx;
    const int* ecol = eidx + NE;

    const int wave = threadIdx.x >> 6;
    const int lane = threadIdx.x & 63;
    const int lm   = lane & 15;
    const int lq4  = lane >> 4;

    // ---------------- phase 0: zero sums+hist, x->bf16, pack weights -------
    {
        uint4 z = {0u, 0u, 0u, 0u};
        uint4* zp = (uint4*)sums;            // sums+hist contiguous: 5,160,000 B
        for (int i = tid; i < 322500; i += nth) zp[i] = z;

        const nfloat4* xs = (const nfloat4*)x;
        uint4* xd = (uint4*)xbf;
        for (int i = tid; i < 160000; i += nth)
            xd[i] = __builtin_bit_cast(uint4, cvt8(xs[i * 2], xs[i * 2 + 1]));

        if (tid < 12288) {
            const float* src; unsigned short* dst; int t, nks;
            if (tid < 4096)       { src = W1a; dst = wp1a; t = tid;         nks = 8; }
            else if (tid < 6144)  { src = W1b; dst = wp1b; t = tid - 4096;  nks = 4; }
            else if (tid < 10240) { src = W2a; dst = wp2a; t = tid - 6144;  nks = 8; }
            else                  { src = W2b; dst = wp2b; t = tid - 10240; nks = 4; }
            const int f = t >> 6, l = t & 63;
            const int ct = f / nks, ks = f - ct * nks;
            const int n  = ct * 16 + (l & 15);
            const int k0 = ks * 32 + (l >> 4) * 8;
            unsigned short tmp[8];
#pragma unroll
            for (int j = 0; j < 8; ++j)
                tmp[j] = f2bf(src[(k0 + j) * 128 + n]);
            *(uint4*)&dst[t * 8] = *(const uint4*)tmp;
        }
    }
    __threadfence();
    gridg.sync();

    // ---------------- phase 1: histogram ----------------------------------
    for (int e = tid; e < NE; e += nth)
        atomicAdd(&hist[erow[e]], 1);
    __threadfence();
    gridg.sync();

    // ---------------- phase 2: scan (block 0 only) ------------------------
    if (blockIdx.x == 0) {
        int* partials = (int*)smem;
        const int t = threadIdx.x;
        const int base = t * 40;
        int s = 0;
        for (int i = 0; i < 40; ++i) {
            int b = base + i;
            if (b < NN) s += hist[b];
        }
        partials[t] = s;
        __syncthreads();
        int pre = 0;
        for (int i = 0; i < t; ++i) pre += partials[i];
        int run = pre;
        for (int i = 0; i < 40; ++i) {
            int b = base + i;
            if (b < NN) {
                row_start[b] = run;
                cursor[b] = run;
                run += hist[b];
            }
        }
        if (t == 255) row_start[NN] = NE;
    }
    __threadfence();
    gridg.sync();

    // ---------------- phase 3: scatter ------------------------------------
    for (int e = tid; e < NE; e += nth) {
        int p = atomicAdd(&cursor[erow[e]], 1);
        perm[p] = e;
    }
    __threadfence();
    gridg.sync();

    // ---------------- phase 4: edge tiles (persistent, XCD-chunked) -------
    {
        float* accbuf = smem;                                   // [64][132] f32
        unsigned short (*Atile)[KA + 8] =
            (unsigned short (*)[KA + 8])smem;                   // aliases accbuf
        unsigned short* Tt = (unsigned short*)smem + 16896;     // [64][136] bf16
        int* rows_s = (int*)((char*)smem + 51200);              // [64]

        const int xcd = blockIdx.x & 7;
        const int lx  = blockIdx.x >> 3;
        const int pxb = nb >> 3;                                // blocks per xcd
        const int t1  = xcd * 1250 + 1250;

        for (int tile = xcd * 1250 + lx; tile < t1; tile += pxb) {
            const int e0 = tile * 64;
            if (threadIdx.x < 64)
                rows_s[threadIdx.x] = erow[perm[e0 + threadIdx.x]];

            // stage A = [xbf[col] | cvt(eattr)] into own wave's 16 rows
            {
                const int lrow = lane >> 2;
                const int lq   = lane & 3;
                const int e = perm[e0 + wave * 16 + lrow];
                const int scol = ecol[e];
                const uint4* xr = (const uint4*)(xbf + (size_t)scol * NF);
                const nfloat4* ar = (const nfloat4*)(eattr + (size_t)e * NH);
                unsigned short* Ar = &Atile[wave * 16 + lrow][0];
#pragma unroll
                for (int it = 0; it < 4; ++it) {
                    const int g = lq + it * 4;
                    *(uint4*)&Ar[g * 8] = xr[g];
                }
#pragma unroll
                for (int it = 0; it < 4; ++it) {
                    const int g = lq + it * 4;
                    nfloat4 v0 = __builtin_nontemporal_load(ar + g * 2);
                    nfloat4 v1 = __builtin_nontemporal_load(ar + g * 2 + 1);
                    *(uint4*)&Ar[128 + g * 8] = __builtin_bit_cast(uint4, cvt8(v0, v1));
                }
            }
            lds_fence();   // own-wave staging -> own-wave frag reads

            bf16x8 a1[8];
#pragma unroll
            for (int ks = 0; ks < 8; ++ks)
                a1[ks] = load_frag(&Atile[wave * 16 + lm][ks * 32 + lq4 * 8]);

            floatx4 acc1[8];
#pragma unroll
            for (int ct = 0; ct < 8; ++ct) {
                floatx4 acc = {0.f, 0.f, 0.f, 0.f};
                const unsigned short* wr = wp1a + (ct * 8 * 64 + lane) * 8;
#pragma unroll
                for (int ks = 0; ks < 8; ++ks) {
                    bf16x8 b = load_frag(wr + ks * 512);
                    acc = __builtin_amdgcn_mfma_f32_16x16x32_bf16(a1[ks], b, acc, 0, 0, 0);
                }
                acc1[ct] = acc;
            }

            float sum_[4] = {0, 0, 0, 0}, sq_[4] = {0, 0, 0, 0};
#pragma unroll
            for (int ct = 0; ct < 8; ++ct) {
                const float bb = b1a[ct * 16 + lm];
#pragma unroll
                for (int i = 0; i < 4; ++i) {
                    float v = acc1[ct][i] + bb;
                    v = fmaxf(v, 0.f);
                    acc1[ct][i] = v;
                    sum_[i] += v;
                    sq_[i]  += v * v;
                }
            }
#pragma unroll
            for (int m = 1; m < 16; m <<= 1) {
#pragma unroll
                for (int i = 0; i < 4; ++i) {
                    sum_[i] += __shfl_xor(sum_[i], m, 64);
                    sq_[i]  += __shfl_xor(sq_[i],  m, 64);
                }
            }
            float mu[4], rs[4];
#pragma unroll
            for (int i = 0; i < 4; ++i) {
                mu[i] = sum_[i] * (1.f / NH);
                float var = sq_[i] * (1.f / NH) - mu[i] * mu[i];
                rs[i] = rsqrtf(var + LN_EPS);
            }

#pragma unroll
            for (int ct = 0; ct < 8; ++ct) {
                const int c = ct * 16 + lm;
                const float gg = g1[c], bb = be1[c];
#pragma unroll
                for (int i = 0; i < 4; ++i) {
                    float nv = (acc1[ct][i] - mu[i]) * rs[i] * gg + bb;
                    Tt[(wave * 16 + lq4 * 4 + i) * 136 + c] = f2bf(nv);
                }
            }
            lds_fence();   // own-wave Ttile -> own-wave a2 reads

            bf16x8 a2[4];
#pragma unroll
            for (int ks = 0; ks < 4; ++ks)
                a2[ks] = load_frag(&Tt[(wave * 16 + lm) * 136 + ks * 32 + lq4 * 8]);

#pragma unroll
            for (int ct = 0; ct < 8; ++ct) {
                floatx4 acc = {0.f, 0.f, 0.f, 0.f};
                const unsigned short* wr = wp1b + (ct * 4 * 64 + lane) * 8;
#pragma unroll
                for (int ks = 0; ks < 4; ++ks) {
                    bf16x8 b = load_frag(wr + ks * 512);
                    acc = __builtin_amdgcn_mfma_f32_16x16x32_bf16(a2[ks], b, acc, 0, 0, 0);
                }
                const int c = ct * 16 + lm;
#pragma unroll
                for (int i = 0; i < 4; ++i)
                    accbuf[(wave * 16 + lq4 * 4 + i) * 132 + c] = acc[i];
            }
            __syncthreads();   // accbuf + rows_s complete -> cross-wave read

            {
                const int t = threadIdx.x;
                const int cc = t & 127;
                const int jb = (t >> 7) * 32;
                float a = 0.f;
                int cur = rows_s[jb];
#pragma unroll 4
                for (int j = jb; j < jb + 32; ++j) {
                    a += accbuf[j * 132 + cc];
                    int nxt = (j + 1 < jb + 32) ? rows_s[j + 1] : -1;
                    if (nxt != cur) {
                        atomicAdd(&sums[cur * NH + cc], a);
                        a = 0.f;
                        cur = nxt;
                    }
                }
            }
            __syncthreads();   // reduction done before next tile's staging
        }
    }
    __threadfence();
    gridg.sync();

    // ---------------- phase 5: node tiles ---------------------------------
    if (blockIdx.x < NNT) {
        unsigned short (*Atile)[KA + 8] = (unsigned short (*)[KA + 8])smem;
        unsigned short* Tt = (unsigned short*)smem + 16896;
        const int n0 = blockIdx.x * 64 + wave * 16;

        {
            const int lrow = lane >> 2;
            const int lq   = lane & 3;
            int n = n0 + lrow;
            if (n >= NN) n = NN - 1;
            const int cntn = row_start[n + 1] - row_start[n];
            const float inv  = (cntn > 0) ? (1.f / (float)cntn) : 1.f;
            const float addb = (cntn > 0) ? 1.f : 0.f;
            const uint4* xr = (const uint4*)(xbf + (size_t)n * NF);
            const nfloat4* sr = (const nfloat4*)(sums + (size_t)n * NH);
            const nfloat4* br = (const nfloat4*)b1b;
            unsigned short* Ar = &Atile[wave * 16 + lrow][0];
#pragma unroll
            for (int it = 0; it < 4; ++it) {
                const int g = lq + it * 4;
                *(uint4*)&Ar[g * 8] = xr[g];
            }
#pragma unroll
            for (int it = 0; it < 4; ++it) {
                const int g = lq + it * 4;
                nfloat4 s0 = sr[g * 2], s1 = sr[g * 2 + 1];
                nfloat4 c0 = br[g * 2], c1 = br[g * 2 + 1];
                nfloat4 u0, u1;
                u0.x = s0.x * inv + addb * c0.x;  u0.y = s0.y * inv + addb * c0.y;
                u0.z = s0.z * inv + addb * c0.z;  u0.w = s0.w * inv + addb * c0.w;
                u1.x = s1.x * inv + addb * c1.x;  u1.y = s1.y * inv + addb * c1.y;
                u1.z = s1.z * inv + addb * c1.z;  u1.w = s1.w * inv + addb * c1.w;
                *(uint4*)&Ar[128 + g * 8] = __builtin_bit_cast(uint4, cvt8(u0, u1));
            }
        }
        __syncthreads();

        bf16x8 a1[8];
#pragma unroll
        for (int ks = 0; ks < 8; ++ks)
            a1[ks] = load_frag(&Atile[wave * 16 + lm][ks * 32 + lq4 * 8]);

        floatx4 acc1[8];
#pragma unroll
        for (int ct = 0; ct < 8; ++ct) {
            floatx4 acc = {0.f, 0.f, 0.f, 0.f};
            const unsigned short* wr = wp2a + (ct * 8 * 64 + lane) * 8;
#pragma unroll
            for (int ks = 0; ks < 8; ++ks) {
                bf16x8 b = load_frag(wr + ks * 512);
                acc = __builtin_amdgcn_mfma_f32_16x16x32_bf16(a1[ks], b, acc, 0, 0, 0);
            }
            acc1[ct] = acc;
        }

        float sum_[4] = {0, 0, 0, 0}, sq_[4] = {0, 0, 0, 0};
#pragma unroll
        for (int ct = 0; ct < 8; ++ct) {
            const float bb = b2a[ct * 16 + lm];
#pragma unroll
            for (int i = 0; i < 4; ++i) {
                float v = acc1[ct][i] + bb;
                v = fmaxf(v, 0.f);
                acc1[ct][i] = v;
                sum_[i] += v;
                sq_[i]  += v * v;
            }
        }
#pragma unroll
        for (int m = 1; m < 16; m <<= 1) {
#pragma unroll
            for (int i = 0; i < 4; ++i) {
                sum_[i] += __shfl_xor(sum_[i], m, 64);
                sq_[i]  += __shfl_xor(sq_[i],  m, 64);
            }
        }
        float mu[4], rs[4];
#pragma unroll
        for (int i = 0; i < 4; ++i) {
            mu[i] = sum_[i] * (1.f / NH);
            float var = sq_[i] * (1.f / NH) - mu[i] * mu[i];
            rs[i] = rsqrtf(var + LN_EPS);
        }
#pragma unroll
        for (int ct = 0; ct < 8; ++ct) {
            const int c = ct * 16 + lm;
            const float gg = g2[c], bb = be2[c];
#pragma unroll
            for (int i = 0; i < 4; ++i) {
                float nv = (acc1[ct][i] - mu[i]) * rs[i] * gg + bb;
                Tt[(wave * 16 + lq4 * 4 + i) * 136 + c] = f2bf(nv);
            }
        }
        __syncthreads();

        bf16x8 a2[4];
#pragma unroll
        for (int ks = 0; ks < 4; ++ks)
            a2[ks] = load_frag(&Tt[(wave * 16 + lm) * 136 + ks * 32 + lq4 * 8]);

#pragma unroll
        for (int ct = 0; ct < 8; ++ct) {
            floatx4 acc = {0.f, 0.f, 0.f, 0.f};
            const unsigned short* wr = wp2b + (ct * 4 * 64 + lane) * 8;
#pragma unroll
            for (int ks = 0; ks < 4; ++ks) {
                bf16x8 b = load_frag(wr + ks * 512);
                acc = __builtin_amdgcn_mfma_f32_16x16x32_bf16(a2[ks], b, acc, 0, 0, 0);
            }
            const int c = ct * 16 + lm;
            const float bb = b2b[c];
#pragma unroll
            for (int i = 0; i < 4; ++i) {
                int n = n0 + lq4 * 4 + i;
                if (n < NN) out[n * NT + c] = acc[i] + bb;
            }
        }
    }
}

// ===========================================================================
// Legacy multi-kernel path (fallback if cooperative launch unavailable).
// ===========================================================================
__global__ __launch_bounds__(256) void conv_weights(
    const float* __restrict__ W1a, const float* __restrict__ W1b,
    const float* __restrict__ W2a, const float* __restrict__ W2b,
    unsigned short* __restrict__ wp1a, unsigned short* __restrict__ wp1b,
    unsigned short* __restrict__ wp2a, unsigned short* __restrict__ wp2b)
{
    int tid = blockIdx.x * 256 + threadIdx.x;
    const float* src;
    unsigned short* dst;
    int t, nks;
    if (tid < 4096)        { src = W1a; dst = wp1a; t = tid;         nks = 8; }
    else if (tid < 6144)   { src = W1b; dst = wp1b; t = tid - 4096;  nks = 4; }
    else if (tid < 10240)  { src = W2a; dst = wp2a; t = tid - 6144;  nks = 8; }
    else if (tid < 12288)  { src = W2b; dst = wp2b; t = tid - 10240; nks = 4; }
    else return;

    const int f = t >> 6, l = t & 63;
    const int ct = f / nks, ks = f - ct * nks;
    const int n  = ct * 16 + (l & 15);
    const int k0 = ks * 32 + (l >> 4) * 8;
    unsigned short tmp[8];
#pragma unroll
    for (int j = 0; j < 8; ++j)
        tmp[j] = f2bf(src[(k0 + j) * 128 + n]);
    *(uint4*)&dst[t * 8] = *(const uint4*)tmp;
}

__global__ __launch_bounds__(256) void hist_kernel(
    const int* __restrict__ row, int* __restrict__ hist)
{
    int e = blockIdx.x * 256 + threadIdx.x;
    if (e < NE) atomicAdd(&hist[row[e]], 1);
}

__global__ __launch_bounds__(256) void scan_kernel(
    const int* __restrict__ hist, int* __restrict__ row_start,
    int* __restrict__ cursor)
{
    __shared__ int partials[256];
    const int t = threadIdx.x;
    const int base = t * 40;
    int s = 0;
    for (int i = 0; i < 40; ++i) {
        int b = base + i;
        if (b < NN) s += hist[b];
    }
    partials[t] = s;
    __syncthreads();
    int pre = 0;
    for (int i = 0; i < t; ++i) pre += partials[i];
    int run = pre;
    for (int i = 0; i < 40; ++i) {
        int b = base + i;
        if (b < NN) {
            row_start[b] = run;
            cursor[b] = run;
            run += hist[b];
        }
    }
    if (t == 255) row_start[NN] = NE;
}

__global__ __launch_bounds__(256) void scatter_kernel(
    const int* __restrict__ row, int* __restrict__ cursor,
    int* __restrict__ perm)
{
    int e = blockIdx.x * 256 + threadIdx.x;
    if (e < NE) {
        int p = atomicAdd(&cursor[row[e]], 1);
        perm[p] = e;
    }
}

__global__ __launch_bounds__(256) void edge_mlp_kernel(
    const float* __restrict__ x,
    const int* __restrict__ erow, const int* __restrict__ ecol,
    const float* __restrict__ eattr,
    const int* __restrict__ perm,
    const unsigned short* __restrict__ wp1a, const float* __restrict__ b1a,
    const float* __restrict__ g1, const float* __restrict__ be1,
    const unsigned short* __restrict__ wp1b,
    float* __restrict__ sums)
{
    __shared__ float accbuf[64][132];
    __shared__ unsigned short Ttile[4][16][NH + 8];
    __shared__ int rows_s[64];
    unsigned short (*Atile)[16][KA + 8] = (unsigned short (*)[16][KA + 8])accbuf;

    const int wave = threadIdx.x >> 6;
    const int lane = threadIdx.x & 63;
    const int e0 = blockIdx.x * 64 + wave * 16;

    if (threadIdx.x < 64) {
        int e = perm[blockIdx.x * 64 + threadIdx.x];
        rows_s[threadIdx.x] = erow[e];
    }

    {
        const int lrow = lane >> 2;
        const int lq   = lane & 3;
        const int e = perm[e0 + lrow];
        const int src = ecol[e];
        const nfloat4* xr = (const nfloat4*)(x + src * NF);
        const nfloat4* ar = (const nfloat4*)(eattr + (size_t)e * NH);
        unsigned short* Ar = &Atile[wave][lrow][0];
#pragma unroll
        for (int it = 0; it < 8; ++it) {
            int c4 = lq + it * 4;
            nfloat4 v = xr[c4];
            uint2 w;
            w.x = (unsigned)f2bf(v.x) | ((unsigned)f2bf(v.y) << 16);
            w.y = (unsigned)f2bf(v.z) | ((unsigned)f2bf(v.w) << 16);
            *(uint2*)&Ar[c4 * 4] = w;
            nfloat4 v2 = __builtin_nontemporal_load(ar + c4);
            uint2 w2;
            w2.x = (unsigned)f2bf(v2.x) | ((unsigned)f2bf(v2.y) << 16);
            w2.y = (unsigned)f2bf(v2.z) | ((unsigned)f2bf(v2.w) << 16);
            *(uint2*)&Ar[128 + c4 * 4] = w2;
        }
    }
    __syncthreads();

    const int lm  = lane & 15;
    const int lq4 = lane >> 4;

    bf16x8 a1[8];
#pragma unroll
    for (int ks = 0; ks < 8; ++ks)
        a1[ks] = load_frag(&Atile[wave][lm][ks * 32 + lq4 * 8]);

    floatx4 acc1[8];
#pragma unroll
    for (int ct = 0; ct < 8; ++ct) {
        floatx4 acc = {0.f, 0.f, 0.f, 0.f};
        const unsigned short* wr = wp1a + (ct * 8 * 64 + lane) * 8;
#pragma unroll
        for (int ks = 0; ks < 8; ++ks) {
            bf16x8 b = load_frag(wr + ks * 512);
            acc = __builtin_amdgcn_mfma_f32_16x16x32_bf16(a1[ks], b, acc, 0, 0, 0);
        }
        acc1[ct] = acc;
    }

    float sum_[4] = {0, 0, 0, 0}, sq_[4] = {0, 0, 0, 0};
#pragma unroll
    for (int ct = 0; ct < 8; ++ct) {
        const float bb = b1a[ct * 16 + lm];
#pragma unroll
        for (int i = 0; i < 4; ++i) {
            float v = acc1[ct][i] + bb;
            v = fmaxf(v, 0.f);
            acc1[ct][i] = v;
            sum_[i] += v;
            sq_[i]  += v * v;
        }
    }
#pragma unroll
    for (int m = 1; m < 16; m <<= 1) {
#pragma unroll
        for (int i = 0; i < 4; ++i) {
            sum_[i] += __shfl_xor(sum_[i], m, 64);
            sq_[i]  += __shfl_xor(sq_[i],  m, 64);
        }
    }
    float mu[4], rs[4];
#pragma unroll
    for (int i = 0; i < 4; ++i) {
        mu[i] = sum_[i] * (1.f / NH);
        float var = sq_[i] * (1.f / NH) - mu[i] * mu[i];
        rs[i] = rsqrtf(var + LN_EPS);
    }
#pragma unroll
    for (int ct = 0; ct < 8; ++ct) {
        const int c = ct * 16 + lm;
        const float gg = g1[c], bb = be1[c];
#pragma unroll
        for (int i = 0; i < 4; ++i) {
            float nv = (acc1[ct][i] - mu[i]) * rs[i] * gg + bb;
            Ttile[wave][lq4 * 4 + i][c] = f2bf(nv);
        }
    }
    __syncthreads();

    bf16x8 a2[4];
#pragma unroll
    for (int ks = 0; ks < 4; ++ks)
        a2[ks] = load_frag(&Ttile[wave][lm][ks * 32 + lq4 * 8]);

#pragma unroll
    for (int ct = 0; ct < 8; ++ct) {
        floatx4 acc = {0.f, 0.f, 0.f, 0.f};
        const unsigned short* wr = wp1b + (ct * 4 * 64 + lane) * 8;
#pragma unroll
        for (int ks = 0; ks < 4; ++ks) {
            bf16x8 b = load_frag(wr + ks * 512);
            acc = __builtin_amdgcn_mfma_f32_16x16x32_bf16(a2[ks], b, acc, 0, 0, 0);
        }
        const int c = ct * 16 + lm;
#pragma unroll
        for (int i = 0; i < 4; ++i)
            accbuf[wave * 16 + lq4 * 4 + i][c] = acc[i];
    }
    __syncthreads();

    {
        const int t = threadIdx.x;
        const int c = t & 127;
        const int jb = (t >> 7) * 32;
        float a = 0.f;
        int cur = rows_s[jb];
#pragma unroll 4
        for (int j = jb; j < jb + 32; ++j) {
            a += accbuf[j][c];
            int nxt = (j + 1 < jb + 32) ? rows_s[j + 1] : -1;
            if (nxt != cur) {
                atomicAdd(&sums[cur * NH + c], a);
                a = 0.f;
                cur = nxt;
            }
        }
    }
}

__global__ __launch_bounds__(256) void node_mlp_kernel(
    const float* __restrict__ x,
    const float* __restrict__ sums, const int* __restrict__ row_start,
    const float* __restrict__ b1b,
    const unsigned short* __restrict__ wp2a, const float* __restrict__ b2a,
    const float* __restrict__ g2, const float* __restrict__ be2,
    const unsigned short* __restrict__ wp2b, const float* __restrict__ b2b,
    float* __restrict__ out)
{
    __shared__ unsigned short Atile[4][16][KA + 8];
    __shared__ unsigned short Ttile[4][16][NH + 8];

    const int wave = threadIdx.x >> 6;
    const int lane = threadIdx.x & 63;
    const int n0 = blockIdx.x * 64 + wave * 16;

    {
        const int lrow = lane >> 2;
        const int lq   = lane & 3;
        int n = n0 + lrow;
        if (n >= NN) n = NN - 1;
        const int cntn = row_start[n + 1] - row_start[n];
        const float inv  = (cntn > 0) ? (1.f / (float)cntn) : 1.f;
        const float addb = (cntn > 0) ? 1.f : 0.f;
        const float4* xr = (const float4*)(x + n * NF);
        const float4* sr = (const float4*)(sums + n * NH);
        const float4* br = (const float4*)b1b;
        unsigned short* Ar = &Atile[wave][lrow][0];
#pragma unroll
        for (int it = 0; it < 8; ++it) {
            int c4 = lq + it * 4;
            float4 v = xr[c4];
            uint2 w;
            w.x = (unsigned)f2bf(v.x) | ((unsigned)f2bf(v.y) << 16);
            w.y = (unsigned)f2bf(v.z) | ((unsigned)f2bf(v.w) << 16);
            *(uint2*)&Ar[c4 * 4] = w;
            float4 v2 = sr[c4];
            float4 bv = br[c4];
            float a0 = v2.x * inv + addb * bv.x;
            float a1 = v2.y * inv + addb * bv.y;
            float a2 = v2.z * inv + addb * bv.z;
            float a3 = v2.w * inv + addb * bv.w;
            uint2 w2;
            w2.x = (unsigned)f2bf(a0) | ((unsigned)f2bf(a1) << 16);
            w2.y = (unsigned)f2bf(a2) | ((unsigned)f2bf(a3) << 16);
            *(uint2*)&Ar[128 + c4 * 4] = w2;
        }
    }
    __syncthreads();

    const int lm  = lane & 15;
    const int lq4 = lane >> 4;

    bf16x8 a1[8];
#pragma unroll
    for (int ks = 0; ks < 8; ++ks)
        a1[ks] = load_frag(&Atile[wave][lm][ks * 32 + lq4 * 8]);

    floatx4 acc1[8];
#pragma unroll
    for (int ct = 0; ct < 8; ++ct) {
        floatx4 acc = {0.f, 0.f, 0.f, 0.f};
        const unsigned short* wr = wp2a + (ct * 8 * 64 + lane) * 8;
#pragma unroll
        for (int ks = 0; ks < 8; ++ks) {
            bf16x8 b = load_frag(wr + ks * 512);
            acc = __builtin_amdgcn_mfma_f32_16x16x32_bf16(a1[ks], b, acc, 0, 0, 0);
        }
        acc1[ct] = acc;
    }

    float sum_[4] = {0, 0, 0, 0}, sq_[4] = {0, 0, 0, 0};
#pragma unroll
    for (int ct = 0; ct < 8; ++ct) {
        const float bb = b2a[ct * 16 + lm];
#pragma unroll
        for (int i = 0; i < 4; ++i) {
            float v = acc1[ct][i] + bb;
            v = fmaxf(v, 0.f);
            acc1[ct][i] = v;
            sum_[i] += v;
            sq_[i]  += v * v;
        }
    }
#pragma unroll
    for (int m = 1; m < 16; m <<= 1) {
#pragma unroll
        for (int i = 0; i < 4; ++i) {
            sum_[i] += __shfl_xor(sum_[i], m, 64);
            sq_[i]  += __shfl_xor(sq_[i],  m, 64);
        }
    }
    float mu[4], rs[4];
#pragma unroll
    for (int i = 0; i < 4; ++i) {
        mu[i] = sum_[i] * (1.f / NH);
        float var = sq_[i] * (1.f / NH) - mu[i] * mu[i];
        rs[i] = rsqrtf(var + LN_EPS);
    }
#pragma unroll
    for (int ct = 0; ct < 8; ++ct) {
        const int c = ct * 16 + lm;
        const float gg = g2[c], bb = be2[c];
#pragma unroll
        for (int i = 0; i < 4; ++i) {
            float nv = (acc1[ct][i] - mu[i]) * rs[i] * gg + bb;
            Ttile[wave][lq4 * 4 + i][c] = f2bf(nv);
        }
    }
    __syncthreads();

    bf16x8 a2[4];
#pragma unroll
    for (int ks = 0; ks < 4; ++ks)
        a2[ks] = load_frag(&Ttile[wave][lm][ks * 32 + lq4 * 8]);

#pragma unroll
    for (int ct = 0; ct < 8; ++ct) {
        floatx4 acc = {0.f, 0.f, 0.f, 0.f};
        const unsigned short* wr = wp2b + (ct * 4 * 64 + lane) * 8;
#pragma unroll
        for (int ks = 0; ks < 4; ++ks) {
            bf16x8 b = load_frag(wr + ks * 512);
            acc = __builtin_amdgcn_mfma_f32_16x16x32_bf16(a2[ks], b, acc, 0, 0, 0);
        }
        const int c = ct * 16 + lm;
        const float bb = b2b[c];
#pragma unroll
        for (int i = 0; i < 4; ++i) {
            int n = n0 + lq4 * 4 + i;
            if (n < NN) out[n * NT + c] = acc[i] + bb;
        }
    }
}

// ---------------------------------------------------------------------------
// Workspace layout (bytes):
//   [0,          5,120,000)  sums      f32 [10000][128]
//   [5,120,000,  5,160,000)  hist      int [10000]
//   [5,160,000,  5,200,000)  cursor    int [10000]
//   [5,200,000,  5,240,064)  row_start int [10001] (padded)
//   [5,240,064,  7,800,064)  perm      int [640000]
//   [7,800,064,  7,865,600)  wp1a      bf16 frag-packed [64][64][8]
//   [7,865,600,  7,898,368)  wp1b      bf16 frag-packed [32][64][8]
//   [7,898,368,  7,963,904)  wp2a      bf16 frag-packed [64][64][8]
//   [7,963,904,  7,996,672)  wp2b      bf16 frag-packed [32][64][8]
//   [7,996,672, 10,556,672)  xbf       bf16 [10000][128]
// ---------------------------------------------------------------------------
extern "C" void kernel_launch(void* const* d_in, const int* in_sizes, int n_in,
                              void* d_out, int out_size, void* d_ws, size_t ws_size,
                              hipStream_t stream) {
    const float* x     = (const float*)d_in[0];
    const int*   eidx  = (const int*)d_in[1];
    const float* eattr = (const float*)d_in[2];
    const float* W1a = (const float*)d_in[3];
    const float* b1a = (const float*)d_in[4];
    const float* g1  = (const float*)d_in[5];
    const float* be1 = (const float*)d_in[6];
    const float* W1b = (const float*)d_in[7];
    const float* b1b = (const float*)d_in[8];
    const float* W2a = (const float*)d_in[9];
    const float* b2a = (const float*)d_in[10];
    const float* g2  = (const float*)d_in[11];
    const float* be2 = (const float*)d_in[12];
    const float* W2b = (const float*)d_in[13];
    const float* b2b = (const float*)d_in[14];

    char* ws = (char*)d_ws;
    float* sums      = (float*)ws;
    int*   hist      = (int*)(ws + 5120000);
    int*   cursor    = (int*)(ws + 5160000);
    int*   row_start = (int*)(ws + 5200000);
    int*   perm      = (int*)(ws + 5240064);
    unsigned short* wp1a = (unsigned short*)(ws + 7800064);
    unsigned short* wp1b = (unsigned short*)(ws + 7865600);
    unsigned short* wp2a = (unsigned short*)(ws + 7898368);
    unsigned short* wp2b = (unsigned short*)(ws + 7963904);
    unsigned short* xbf  = (unsigned short*)(ws + 7996672);
    float* out = (float*)d_out;

    const int* erow = eidx;
    const int* ecol = eidx + NE;

    static int nblocks = 0;   // 0 = unprobed, -1 = legacy
    if (nblocks == 0) {
        int dev = 0;
        (void)hipGetDevice(&dev);
        int coop = 0;
        (void)hipDeviceGetAttribute(&coop, hipDeviceAttributeCooperativeLaunch, dev);
        int maxb = 0;
        if (coop && ws_size >= 10556672) {
            if (hipOccupancyMaxActiveBlocksPerMultiprocessor(&maxb, fused_kernel, 256, 0)
                != hipSuccess) maxb = 0;
        }
        if (maxb >= 3)      nblocks = 768;
        else if (maxb == 2) nblocks = 512;
        else if (maxb == 1) nblocks = 256;
        else                nblocks = -1;
    }

    if (nblocks > 0) {
        void* args[] = {
            (void*)&x, (void*)&eidx, (void*)&eattr,
            (void*)&W1a, (void*)&b1a, (void*)&g1, (void*)&be1,
            (void*)&W1b, (void*)&b1b,
            (void*)&W2a, (void*)&b2a, (void*)&g2, (void*)&be2,
            (void*)&W2b, (void*)&b2b,
            (void*)&sums, (void*)&hist, (void*)&cursor,
            (void*)&row_start, (void*)&perm,
            (void*)&wp1a, (void*)&wp1b, (void*)&wp2a, (void*)&wp2b,
            (void*)&xbf, (void*)&out
        };
        hipError_t err = hipLaunchCooperativeKernel((void*)fused_kernel,
                                                    dim3(nblocks), dim3(256),
                                                    args, 0, stream);
        if (err == hipSuccess) return;
        nblocks = -1;   // permanent fallback
    }

    // ---- legacy path ----
    (void)hipMemsetAsync(ws, 0, 5160000, stream);
    conv_weights<<<48, 256, 0, stream>>>(W1a, W1b, W2a, W2b, wp1a, wp1b, wp2a, wp2b);
    hist_kernel<<<(NE + 255) / 256, 256, 0, stream>>>(erow, hist);
    scan_kernel<<<1, 256, 0, stream>>>(hist, row_start, cursor);
    scatter_kernel<<<(NE + 255) / 256, 256, 0, stream>>>(erow, cursor, perm);
    edge_mlp_kernel<<<NE / 64, 256, 0, stream>>>(x, erow, ecol, eattr, perm,
                                                 wp1a, b1a, g1, be1, wp1b, sums);
    node_mlp_kernel<<<(NN + 63) / 64, 256, 0, stream>>>(x, sums, row_start, b1b,
                                                        wp2a, b2a, g2, be2, wp2b, b2b,
                                                        out);
}

// Round 5
// 1062.574 us; speedup vs baseline: 1.8809x; 1.8809x over previous
//
#include <hip/hip_runtime.h>
#include <hip/hip_bf16.h>

#define NN 10000
#define NE 640000
#define NF 128
#define NH 128
#define NT 128
#define KA 256   // NF + NH
#define LN_EPS 1e-5f
#define TPB 14   // tiles (64 edges) per persistent edge block
#define NBE 715  // ceil(10000 tiles / TPB); 715*14 = 10010 >= 10000

typedef __bf16 bf16x8 __attribute__((ext_vector_type(8)));
typedef float floatx4 __attribute__((ext_vector_type(4)));
typedef float nfloat4 __attribute__((ext_vector_type(4)));

__device__ inline unsigned short f2bf(float f) {
    unsigned int u = __float_as_uint(f);
    u += 0x7FFFu + ((u >> 16) & 1u);   // round-to-nearest-even
    return (unsigned short)(u >> 16);
}

__device__ inline bf16x8 load_frag(const unsigned short* p) {
    uint4 u = *(const uint4*)p;
    return __builtin_bit_cast(bf16x8, u);
}

// native casts -> v_cvt_pk_bf16_f32 (RTNE), 2 floats/instr
__device__ inline bf16x8 cvt8(nfloat4 v0, nfloat4 v1) {
    bf16x8 r;
    r[0] = (__bf16)v0.x; r[1] = (__bf16)v0.y; r[2] = (__bf16)v0.z; r[3] = (__bf16)v0.w;
    r[4] = (__bf16)v1.x; r[5] = (__bf16)v1.y; r[6] = (__bf16)v1.z; r[7] = (__bf16)v1.w;
    return r;
}

// wave-local LDS ordering fence; sched_barrier stops hipcc hoisting past it
__device__ inline void lds_fence() {
    asm volatile("s_waitcnt lgkmcnt(0)" ::: "memory");
    __builtin_amdgcn_sched_barrier(0);
}

// ---------------------------------------------------------------------------
// Prep: pack weights f32 [K][N] -> bf16 MFMA-fragment order, and x -> bf16.
// Fragment f=(ct*nks+ks): 64 lanes x 8 elems contiguous (1KB). Lane l holds
// B[k = ks*32 + (l>>4)*8 + j][n = ct*16 + (l&15)].
// ---------------------------------------------------------------------------
__global__ __launch_bounds__(256) void prep_kernel(
    const float* __restrict__ x,
    const float* __restrict__ W1a, const float* __restrict__ W1b,
    const float* __restrict__ W2a, const float* __restrict__ W2b,
    unsigned short* __restrict__ wp1a, unsigned short* __restrict__ wp1b,
    unsigned short* __restrict__ wp2a, unsigned short* __restrict__ wp2b,
    unsigned short* __restrict__ xbf)
{
    const int tid = blockIdx.x * 256 + threadIdx.x;
    const int nth = gridDim.x * 256;

    // x (f32 [10000][128]) -> xbf (bf16), 160000 x 16B
    const nfloat4* xs = (const nfloat4*)x;
    uint4* xd = (uint4*)xbf;
    for (int i = tid; i < 160000; i += nth)
        xd[i] = __builtin_bit_cast(uint4, cvt8(xs[2 * i], xs[2 * i + 1]));

    if (tid < 12288) {
        const float* src; unsigned short* dst; int t, nks;
        if (tid < 4096)       { src = W1a; dst = wp1a; t = tid;         nks = 8; }
        else if (tid < 6144)  { src = W1b; dst = wp1b; t = tid - 4096;  nks = 4; }
        else if (tid < 10240) { src = W2a; dst = wp2a; t = tid - 6144;  nks = 8; }
        else                  { src = W2b; dst = wp2b; t = tid - 10240; nks = 4; }
        const int f = t >> 6, l = t & 63;
        const int ct = f / nks, ks = f - ct * nks;
        const int n  = ct * 16 + (l & 15);
        const int k0 = ks * 32 + (l >> 4) * 8;
        unsigned short tmp[8];
#pragma unroll
        for (int j = 0; j < 8; ++j)
            tmp[j] = f2bf(src[(k0 + j) * 128 + n]);
        *(uint4*)&dst[t * 8] = *(const uint4*)tmp;
    }
}

// ---------------------------------------------------------------------------
// Counting sort by target row: hist -> scan -> scatter.
// ---------------------------------------------------------------------------
__global__ __launch_bounds__(256) void hist_kernel(
    const int* __restrict__ row, int* __restrict__ hist)
{
    int e = blockIdx.x * 256 + threadIdx.x;
    if (e < NE) atomicAdd(&hist[row[e]], 1);
}

__global__ __launch_bounds__(256) void scan_kernel(
    const int* __restrict__ hist, int* __restrict__ row_start,
    int* __restrict__ cursor)
{
    __shared__ int partials[256];
    const int t = threadIdx.x;
    const int base = t * 40;                  // 256*40 = 10240 >= NN
    int s = 0;
    for (int i = 0; i < 40; ++i) {
        int b = base + i;
        if (b < NN) s += hist[b];
    }
    partials[t] = s;
    __syncthreads();
    int pre = 0;
    for (int i = 0; i < t; ++i) pre += partials[i];
    int run = pre;
    for (int i = 0; i < 40; ++i) {
        int b = base + i;
        if (b < NN) {
            row_start[b] = run;
            cursor[b] = run;
            run += hist[b];
        }
    }
    if (t == 255) row_start[NN] = NE;
}

__global__ __launch_bounds__(256) void scatter_kernel(
    const int* __restrict__ row, int* __restrict__ cursor,
    int* __restrict__ perm)
{
    int e = blockIdx.x * 256 + threadIdx.x;
    if (e < NE) {
        int p = atomicAdd(&cursor[row[e]], 1);
        perm[p] = e;
    }
}

// ---------------------------------------------------------------------------
// Edge MLP "R0 + persistent pipeline": 715 co-resident blocks x 14 consecutive
// 64-edge tiles. Per-tile internals = R0 (best measured). New:
//  - eattr(t+1) prefetched into regs right after a1 reads (HBM ~900cy hidden
//    under GEMM1+LN+GEMM2+reduce), x(t+1) prefetched after GEMM1 (L2 ~200cy).
//  - x gathered from pre-converted bf16 xbf (L2-resident, half bytes, no cvt).
//  - R3-proven aliased 34KB LDS (Atile/Ttile/accbuf in one buffer).
// Consecutive tiles = consecutive sorted rows -> sums atomics stay L2-local.
// ---------------------------------------------------------------------------
__global__ __launch_bounds__(256, 3) void edge_mlp_kernel(
    const unsigned short* __restrict__ xbf,
    const int* __restrict__ erow, const int* __restrict__ ecol,
    const float* __restrict__ eattr,
    const int* __restrict__ perm,
    const unsigned short* __restrict__ wp1a, const float* __restrict__ b1a,
    const float* __restrict__ g1, const float* __restrict__ be1,
    const unsigned short* __restrict__ wp1b,
    float* __restrict__ sums)
{
    __shared__ __align__(16) float smem[64 * 132];   // 33792 B, aliased views
    __shared__ int rows_s[64];

    const int wave = threadIdx.x >> 6;
    const int lane = threadIdx.x & 63;
    const int lm   = lane & 15;
    const int lq4  = lane >> 4;
    const int lrow = lane >> 2;          // 0..15: edge slot within wave
    const int lq   = lane & 3;

    unsigned short* At = (unsigned short*)smem;      // [64][264] shorts view
    unsigned short* Tw = At + wave * 16 * 264;       // own wave's chunk

    const int base = blockIdx.x * TPB;

    // ---- prologue prefetch for tile = base ----
    int ecur = perm[base * 64 + wave * 16 + lrow];
    nfloat4 pe[8];
    uint4 px[4];
    {
        const nfloat4* ar = (const nfloat4*)(eattr + (size_t)ecur * NH);
#pragma unroll
        for (int t = 0; t < 4; ++t) {
            const int g = lq + t * 4;
            pe[2 * t]     = __builtin_nontemporal_load(ar + g * 2);
            pe[2 * t + 1] = __builtin_nontemporal_load(ar + g * 2 + 1);
        }
        const uint4* xr = (const uint4*)(xbf + (size_t)ecol[ecur] * NF);
#pragma unroll
        for (int t = 0; t < 4; ++t)
            px[t] = xr[lq + t * 4];
    }

    for (int it = 0; it < TPB; ++it) {
        const int tile = base + it;
        if (tile >= NE / 64) break;
        const bool hasnext = (it + 1 < TPB) && (tile + 1 < NE / 64);

        if (threadIdx.x < 64)
            rows_s[threadIdx.x] = erow[perm[tile * 64 + threadIdx.x]];

        // ---- stage A = [xbf-row | cvt(eattr)] from prefetch regs ----
        {
            unsigned short* Ar = At + (wave * 16 + lrow) * 264;
#pragma unroll
            for (int t = 0; t < 4; ++t)
                *(uint4*)&Ar[(lq + t * 4) * 8] = px[t];
#pragma unroll
            for (int t = 0; t < 4; ++t)
                *(uint4*)&Ar[128 + (lq + t * 4) * 8] =
                    __builtin_bit_cast(uint4, cvt8(pe[2 * t], pe[2 * t + 1]));
        }
        lds_fence();   // own-wave staging -> own-wave frag reads

        bf16x8 a1[8];
#pragma unroll
        for (int ks = 0; ks < 8; ++ks)
            a1[ks] = load_frag(&At[(wave * 16 + lm) * 264 + ks * 32 + lq4 * 8]);

        // ---- prefetch eattr(t+1): pe regs dead after staging cvt ----
        if (hasnext) {
            ecur = perm[(tile + 1) * 64 + wave * 16 + lrow];
            const nfloat4* ar = (const nfloat4*)(eattr + (size_t)ecur * NH);
#pragma unroll
            for (int t = 0; t < 4; ++t) {
                const int g = lq + t * 4;
                pe[2 * t]     = __builtin_nontemporal_load(ar + g * 2);
                pe[2 * t + 1] = __builtin_nontemporal_load(ar + g * 2 + 1);
            }
        }

        // ---- GEMM1: [16 x 256] @ [256 x 128] ----
        floatx4 acc1[8];
#pragma unroll
        for (int ct = 0; ct < 8; ++ct) {
            floatx4 acc = {0.f, 0.f, 0.f, 0.f};
            const unsigned short* wr = wp1a + (ct * 8 * 64 + lane) * 8;
#pragma unroll
            for (int ks = 0; ks < 8; ++ks) {
                bf16x8 b = load_frag(wr + ks * 512);
                acc = __builtin_amdgcn_mfma_f32_16x16x32_bf16(a1[ks], b, acc, 0, 0, 0);
            }
            acc1[ct] = acc;
        }

        // ---- prefetch x(t+1) (L2-resident; covered by LN+GEMM2+reduce) ----
        if (hasnext) {
            const uint4* xr = (const uint4*)(xbf + (size_t)ecol[ecur] * NF);
#pragma unroll
            for (int t = 0; t < 4; ++t)
                px[t] = xr[lq + t * 4];
        }

        // ---- bias + ReLU + per-wave LayerNorm ----
        float sum_[4] = {0, 0, 0, 0}, sq_[4] = {0, 0, 0, 0};
#pragma unroll
        for (int ct = 0; ct < 8; ++ct) {
            const float bb = b1a[ct * 16 + lm];
#pragma unroll
            for (int i = 0; i < 4; ++i) {
                float v = acc1[ct][i] + bb;
                v = fmaxf(v, 0.f);
                acc1[ct][i] = v;
                sum_[i] += v;
                sq_[i]  += v * v;
            }
        }
#pragma unroll
        for (int m = 1; m < 16; m <<= 1) {
#pragma unroll
            for (int i = 0; i < 4; ++i) {
                sum_[i] += __shfl_xor(sum_[i], m, 64);
                sq_[i]  += __shfl_xor(sq_[i],  m, 64);
            }
        }
        float mu[4], rs[4];
#pragma unroll
        for (int i = 0; i < 4; ++i) {
            mu[i] = sum_[i] * (1.f / NH);
            float var = sq_[i] * (1.f / NH) - mu[i] * mu[i];
            rs[i] = rsqrtf(var + LN_EPS);
        }

        // ---- LN apply -> Ttile (overwrites own dead Atile cols 0..127) ----
#pragma unroll
        for (int ct = 0; ct < 8; ++ct) {
            const int c = ct * 16 + lm;
            const float gg = g1[c], bb = be1[c];
#pragma unroll
            for (int i = 0; i < 4; ++i) {
                float nv = (acc1[ct][i] - mu[i]) * rs[i] * gg + bb;
                Tw[(lq4 * 4 + i) * 264 + c] = __builtin_bit_cast(unsigned short, (__bf16)nv);
            }
        }
        lds_fence();   // Ttile writes -> a2 reads

        bf16x8 a2[4];
#pragma unroll
        for (int ks = 0; ks < 4; ++ks)
            a2[ks] = load_frag(&Tw[lm * 264 + ks * 32 + lq4 * 8]);

        // ---- GEMM2: [16 x 128] @ [128 x 128] -> f32 accbuf (stride 132) ----
#pragma unroll
        for (int ct = 0; ct < 8; ++ct) {
            floatx4 acc = {0.f, 0.f, 0.f, 0.f};
            const unsigned short* wr = wp1b + (ct * 4 * 64 + lane) * 8;
#pragma unroll
            for (int ks = 0; ks < 4; ++ks) {
                bf16x8 b = load_frag(wr + ks * 512);
                acc = __builtin_amdgcn_mfma_f32_16x16x32_bf16(a2[ks], b, acc, 0, 0, 0);
            }
            const int c = ct * 16 + lm;
#pragma unroll
            for (int i = 0; i < 4; ++i) {
                const int r = wave * 16 + lq4 * 4 + i;
                smem[r * 132 + c] = acc[i];
            }
        }
        __syncthreads();   // accbuf + rows_s complete -> cross-wave reduce

        // ---- segmented reduction over the tile's 64 sorted edges ----
        {
            const int t = threadIdx.x;
            const int cc = t & 127;
            const int jb = (t >> 7) * 32;
            float a = 0.f;
            int cur = rows_s[jb];
#pragma unroll 4
            for (int j = jb; j < jb + 32; ++j) {
                a += smem[j * 132 + cc];
                int nxt = (j + 1 < jb + 32) ? rows_s[j + 1] : -1;
                if (nxt != cur) {
                    atomicAdd(&sums[cur * NH + cc], a);
                    a = 0.f;
                    cur = nxt;
                }
            }
        }
        __syncthreads();   // reduce reads done before next tile's staging
    }
}

// ---------------------------------------------------------------------------
// Node MLP: A = [x[n] | sums[n]/cnt + b1b (cnt>0)], packed weights.
// ---------------------------------------------------------------------------
__global__ __launch_bounds__(256) void node_mlp_kernel(
    const float* __restrict__ x,
    const float* __restrict__ sums, const int* __restrict__ row_start,
    const float* __restrict__ b1b,
    const unsigned short* __restrict__ wp2a, const float* __restrict__ b2a,
    const float* __restrict__ g2, const float* __restrict__ be2,
    const unsigned short* __restrict__ wp2b, const float* __restrict__ b2b,
    float* __restrict__ out)
{
    __shared__ unsigned short Atile[4][16][KA + 8];
    __shared__ unsigned short Ttile[4][16][NH + 8];

    const int wave = threadIdx.x >> 6;
    const int lane = threadIdx.x & 63;
    const int n0 = blockIdx.x * 64 + wave * 16;

    {
        const int lrow = lane >> 2;
        const int lq   = lane & 3;
        int n = n0 + lrow;
        if (n >= NN) n = NN - 1;
        const int cntn = row_start[n + 1] - row_start[n];
        const float inv  = (cntn > 0) ? (1.f / (float)cntn) : 1.f;
        const float addb = (cntn > 0) ? 1.f : 0.f;
        const float4* xr = (const float4*)(x + n * NF);
        const float4* sr = (const float4*)(sums + n * NH);
        const float4* br = (const float4*)b1b;
        unsigned short* Ar = &Atile[wave][lrow][0];
#pragma unroll
        for (int it = 0; it < 8; ++it) {
            int c4 = lq + it * 4;
            float4 v = xr[c4];
            uint2 w;
            w.x = (unsigned)f2bf(v.x) | ((unsigned)f2bf(v.y) << 16);
            w.y = (unsigned)f2bf(v.z) | ((unsigned)f2bf(v.w) << 16);
            *(uint2*)&Ar[c4 * 4] = w;
            float4 v2 = sr[c4];
            float4 bv = br[c4];
            float a0 = v2.x * inv + addb * bv.x;
            float a1 = v2.y * inv + addb * bv.y;
            float a2 = v2.z * inv + addb * bv.z;
            float a3 = v2.w * inv + addb * bv.w;
            uint2 w2;
            w2.x = (unsigned)f2bf(a0) | ((unsigned)f2bf(a1) << 16);
            w2.y = (unsigned)f2bf(a2) | ((unsigned)f2bf(a3) << 16);
            *(uint2*)&Ar[128 + c4 * 4] = w2;
        }
    }
    __syncthreads();

    const int lm  = lane & 15;
    const int lq4 = lane >> 4;

    bf16x8 a1[8];
#pragma unroll
    for (int ks = 0; ks < 8; ++ks)
        a1[ks] = load_frag(&Atile[wave][lm][ks * 32 + lq4 * 8]);

    floatx4 acc1[8];
#pragma unroll
    for (int ct = 0; ct < 8; ++ct) {
        floatx4 acc = {0.f, 0.f, 0.f, 0.f};
        const unsigned short* wr = wp2a + (ct * 8 * 64 + lane) * 8;
#pragma unroll
        for (int ks = 0; ks < 8; ++ks) {
            bf16x8 b = load_frag(wr + ks * 512);
            acc = __builtin_amdgcn_mfma_f32_16x16x32_bf16(a1[ks], b, acc, 0, 0, 0);
        }
        acc1[ct] = acc;
    }

    float sum_[4] = {0, 0, 0, 0}, sq_[4] = {0, 0, 0, 0};
#pragma unroll
    for (int ct = 0; ct < 8; ++ct) {
        const float bb = b2a[ct * 16 + lm];
#pragma unroll
        for (int i = 0; i < 4; ++i) {
            float v = acc1[ct][i] + bb;
            v = fmaxf(v, 0.f);
            acc1[ct][i] = v;
            sum_[i] += v;
            sq_[i]  += v * v;
        }
    }
#pragma unroll
    for (int m = 1; m < 16; m <<= 1) {
#pragma unroll
        for (int i = 0; i < 4; ++i) {
            sum_[i] += __shfl_xor(sum_[i], m, 64);
            sq_[i]  += __shfl_xor(sq_[i],  m, 64);
        }
    }
    float mu[4], rs[4];
#pragma unroll
    for (int i = 0; i < 4; ++i) {
        mu[i] = sum_[i] * (1.f / NH);
        float var = sq_[i] * (1.f / NH) - mu[i] * mu[i];
        rs[i] = rsqrtf(var + LN_EPS);
    }
#pragma unroll
    for (int ct = 0; ct < 8; ++ct) {
        const int c = ct * 16 + lm;
        const float gg = g2[c], bb = be2[c];
#pragma unroll
        for (int i = 0; i < 4; ++i) {
            float nv = (acc1[ct][i] - mu[i]) * rs[i] * gg + bb;
            Ttile[wave][lq4 * 4 + i][c] = f2bf(nv);
        }
    }
    __syncthreads();

    bf16x8 a2[4];
#pragma unroll
    for (int ks = 0; ks < 4; ++ks)
        a2[ks] = load_frag(&Ttile[wave][lm][ks * 32 + lq4 * 8]);

#pragma unroll
    for (int ct = 0; ct < 8; ++ct) {
        floatx4 acc = {0.f, 0.f, 0.f, 0.f};
        const unsigned short* wr = wp2b + (ct * 4 * 64 + lane) * 8;
#pragma unroll
        for (int ks = 0; ks < 4; ++ks) {
            bf16x8 b = load_frag(wr + ks * 512);
            acc = __builtin_amdgcn_mfma_f32_16x16x32_bf16(a2[ks], b, acc, 0, 0, 0);
        }
        const int c = ct * 16 + lm;
        const float bb = b2b[c];
#pragma unroll
        for (int i = 0; i < 4; ++i) {
            int n = n0 + lq4 * 4 + i;
            if (n < NN) out[n * NT + c] = acc[i] + bb;
        }
    }
}

// ---------------------------------------------------------------------------
// Workspace layout (bytes):
//   [0,          5,120,000)  sums      f32 [10000][128]
//   [5,120,000,  5,160,000)  hist      int [10000]
//   [5,160,000,  5,200,000)  cursor    int [10000]
//   [5,200,000,  5,240,064)  row_start int [10001] (padded)
//   [5,240,064,  7,800,064)  perm      int [640000]
//   [7,800,064,  7,865,600)  wp1a      bf16 frag-packed [64][64][8]
//   [7,865,600,  7,898,368)  wp1b      bf16 frag-packed [32][64][8]
//   [7,898,368,  7,963,904)  wp2a      bf16 frag-packed [64][64][8]
//   [7,963,904,  7,996,672)  wp2b      bf16 frag-packed [32][64][8]
//   [7,996,672, 10,556,672)  xbf       bf16 [10000][128]
// ---------------------------------------------------------------------------
extern "C" void kernel_launch(void* const* d_in, const int* in_sizes, int n_in,
                              void* d_out, int out_size, void* d_ws, size_t ws_size,
                              hipStream_t stream) {
    const float* x     = (const float*)d_in[0];
    const int*   eidx  = (const int*)d_in[1];
    const float* eattr = (const float*)d_in[2];
    const float* W1a = (const float*)d_in[3];
    const float* b1a = (const float*)d_in[4];
    const float* g1  = (const float*)d_in[5];
    const float* be1 = (const float*)d_in[6];
    const float* W1b = (const float*)d_in[7];
    const float* b1b = (const float*)d_in[8];
    const float* W2a = (const float*)d_in[9];
    const float* b2a = (const float*)d_in[10];
    const float* g2  = (const float*)d_in[11];
    const float* be2 = (const float*)d_in[12];
    const float* W2b = (const float*)d_in[13];
    const float* b2b = (const float*)d_in[14];

    char* ws = (char*)d_ws;
    float* sums      = (float*)ws;
    int*   hist      = (int*)(ws + 5120000);
    int*   cursor    = (int*)(ws + 5160000);
    int*   row_start = (int*)(ws + 5200000);
    int*   perm      = (int*)(ws + 5240064);
    unsigned short* wp1a = (unsigned short*)(ws + 7800064);
    unsigned short* wp1b = (unsigned short*)(ws + 7865600);
    unsigned short* wp2a = (unsigned short*)(ws + 7898368);
    unsigned short* wp2b = (unsigned short*)(ws + 7963904);
    unsigned short* xbf  = (unsigned short*)(ws + 7996672);

    const int* erow = eidx;
    const int* ecol = eidx + NE;

    (void)hipMemsetAsync(ws, 0, 5160000, stream);   // zero sums + hist
    prep_kernel<<<640, 256, 0, stream>>>(x, W1a, W1b, W2a, W2b,
                                         wp1a, wp1b, wp2a, wp2b, xbf);
    hist_kernel<<<(NE + 255) / 256, 256, 0, stream>>>(erow, hist);
    scan_kernel<<<1, 256, 0, stream>>>(hist, row_start, cursor);
    scatter_kernel<<<(NE + 255) / 256, 256, 0, stream>>>(erow, cursor, perm);
    edge_mlp_kernel<<<NBE, 256, 0, stream>>>(xbf, erow, ecol, eattr, perm,
                                             wp1a, b1a, g1, be1, wp1b, sums);
    node_mlp_kernel<<<(NN + 63) / 64, 256, 0, stream>>>(x, sums, row_start, b1b,
                                                        wp2a, b2a, g2, be2, wp2b, b2b,
                                                        (float*)d_out);
}

// Round 6
// 747.518 us; speedup vs baseline: 2.6737x; 1.4215x over previous
//
#include <hip/hip_runtime.h>
#include <hip/hip_bf16.h>

#define NN 10000
#define NE 640000
#define NF 128
#define NH 128
#define NT 128
#define KA 256   // NF + NH
#define LN_EPS 1e-5f

typedef __bf16 bf16x8 __attribute__((ext_vector_type(8)));
typedef float floatx4 __attribute__((ext_vector_type(4)));
typedef float nfloat4 __attribute__((ext_vector_type(4)));

__device__ inline unsigned short f2bf(float f) {
    unsigned int u = __float_as_uint(f);
    u += 0x7FFFu + ((u >> 16) & 1u);   // round-to-nearest-even
    return (unsigned short)(u >> 16);
}

__device__ inline bf16x8 load_frag(const unsigned short* p) {
    uint4 u = *(const uint4*)p;
    return __builtin_bit_cast(bf16x8, u);
}

__device__ inline floatx4 mfma16(bf16x8 a, bf16x8 b, floatx4 c) {
    return __builtin_amdgcn_mfma_f32_16x16x32_bf16(a, b, c, 0, 0, 0);
}

// native casts -> v_cvt_pk_bf16_f32 (RTNE), 2 floats/instr
__device__ inline bf16x8 cvt8(nfloat4 v0, nfloat4 v1) {
    bf16x8 r;
    r[0] = (__bf16)v0.x; r[1] = (__bf16)v0.y; r[2] = (__bf16)v0.z; r[3] = (__bf16)v0.w;
    r[4] = (__bf16)v1.x; r[5] = (__bf16)v1.y; r[6] = (__bf16)v1.z; r[7] = (__bf16)v1.w;
    return r;
}

// wave-local LDS ordering fence; sched_barrier stops hipcc hoisting past it
__device__ inline void lds_fence() {
    asm volatile("s_waitcnt lgkmcnt(0)" ::: "memory");
    __builtin_amdgcn_sched_barrier(0);
}

// ---------------------------------------------------------------------------
// Prep: pack weights f32 [K][N] -> bf16 MFMA-fragment order, and x -> bf16.
// Fragment f=(ct*nks+ks): 64 lanes x 8 elems contiguous (1KB). Lane l holds
// B[k = ks*32 + (l>>4)*8 + j][n = ct*16 + (l&15)].
// ---------------------------------------------------------------------------
__global__ __launch_bounds__(256) void prep_kernel(
    const float* __restrict__ x,
    const float* __restrict__ W1a, const float* __restrict__ W1b,
    const float* __restrict__ W2a, const float* __restrict__ W2b,
    unsigned short* __restrict__ wp1a, unsigned short* __restrict__ wp1b,
    unsigned short* __restrict__ wp2a, unsigned short* __restrict__ wp2b,
    unsigned short* __restrict__ xbf)
{
    const int tid = blockIdx.x * 256 + threadIdx.x;
    const int nth = gridDim.x * 256;

    // x (f32 [10000][128]) -> xbf (bf16), 160000 x 16B
    const nfloat4* xs = (const nfloat4*)x;
    uint4* xd = (uint4*)xbf;
    for (int i = tid; i < 160000; i += nth)
        xd[i] = __builtin_bit_cast(uint4, cvt8(xs[2 * i], xs[2 * i + 1]));

    if (tid < 12288) {
        const float* src; unsigned short* dst; int t, nks;
        if (tid < 4096)       { src = W1a; dst = wp1a; t = tid;         nks = 8; }
        else if (tid < 6144)  { src = W1b; dst = wp1b; t = tid - 4096;  nks = 4; }
        else if (tid < 10240) { src = W2a; dst = wp2a; t = tid - 6144;  nks = 8; }
        else                  { src = W2b; dst = wp2b; t = tid - 10240; nks = 4; }
        const int f = t >> 6, l = t & 63;
        const int ct = f / nks, ks = f - ct * nks;
        const int n  = ct * 16 + (l & 15);
        const int k0 = ks * 32 + (l >> 4) * 8;
        unsigned short tmp[8];
#pragma unroll
        for (int j = 0; j < 8; ++j)
            tmp[j] = f2bf(src[(k0 + j) * 128 + n]);
        *(uint4*)&dst[t * 8] = *(const uint4*)tmp;
    }
}

// ---------------------------------------------------------------------------
// Counting sort by target row: hist -> scan -> scatter.
// ---------------------------------------------------------------------------
__global__ __launch_bounds__(256) void hist_kernel(
    const int* __restrict__ row, int* __restrict__ hist)
{
    int e = blockIdx.x * 256 + threadIdx.x;
    if (e < NE) atomicAdd(&hist[row[e]], 1);
}

__global__ __launch_bounds__(256) void scan_kernel(
    const int* __restrict__ hist, int* __restrict__ row_start,
    int* __restrict__ cursor)
{
    __shared__ int partials[256];
    const int t = threadIdx.x;
    const int base = t * 40;                  // 256*40 = 10240 >= NN
    int s = 0;
    for (int i = 0; i < 40; ++i) {
        int b = base + i;
        if (b < NN) s += hist[b];
    }
    partials[t] = s;
    __syncthreads();
    int pre = 0;
    for (int i = 0; i < t; ++i) pre += partials[i];
    int run = pre;
    for (int i = 0; i < 40; ++i) {
        int b = base + i;
        if (b < NN) {
            row_start[b] = run;
            cursor[b] = run;
            run += hist[b];
        }
    }
    if (t == 255) row_start[NN] = NE;
}

__global__ __launch_bounds__(256) void scatter_kernel(
    const int* __restrict__ row, int* __restrict__ cursor,
    int* __restrict__ perm)
{
    int e = blockIdx.x * 256 + threadIdx.x;
    if (e < NE) {
        int p = atomicAdd(&cursor[row[e]], 1);
        perm[p] = e;
    }
}

// ---------------------------------------------------------------------------
// Edge MLP "M32": R0 schedule shape (one tile per block, retire fast; one
// true barrier) but 32 edges PER WAVE (128-edge tiles, grid 5000). Each
// weight B-fragment load from L2 now feeds TWO MFMAs -> weight L2 traffic
// halves (3.8 GB -> 1.9 GB) and per-wave MFMA ILP doubles.
// LDS = exactly 64KB union:
//   Atile: frag-major bf16, frag(w*2+mt, ks) at (((w*2+mt)*8+ks)*64+lane)*8
//   Ttile: per-wave row-major [32][136] bf16 in own dead 16KB chunk
//   accbuf: f32 [128][128], XOR col swizzle (c ^ ((r&7)<<2)) -> conflict-free
// Segmented reduce driven by row_start ranges (no rows_s, wave-uniform).
// ---------------------------------------------------------------------------
__global__ __launch_bounds__(256, 2) void edge_mlp_kernel(
    const unsigned short* __restrict__ xbf,
    const int* __restrict__ erow, const int* __restrict__ ecol,
    const float* __restrict__ eattr,
    const int* __restrict__ perm,
    const unsigned short* __restrict__ wp1a, const float* __restrict__ b1a,
    const float* __restrict__ g1, const float* __restrict__ be1,
    const unsigned short* __restrict__ wp1b,
    const int* __restrict__ row_start,
    float* __restrict__ sums)
{
    __shared__ __align__(16) float smem[16384];   // 65536 B union

    const int wave = threadIdx.x >> 6;
    const int lane = threadIdx.x & 63;
    const int lm   = lane & 15;
    const int lq4  = lane >> 4;
    const int e0   = blockIdx.x * 128;

    unsigned short* At = (unsigned short*)smem;

    // ---- stage A = [xbf[col] | cvt(eattr)] in FRAG-MAJOR layout ----
    // 2 lanes per edge; granule g (8 bf16 = 16B): ks=g>>2, l4=g&3,
    // dst frag = (wave*2 + mt)*8 + ks, lane-slot = l4*16 + (edge&15).
    {
        const int lrow = lane >> 1;          // 0..31: edge within wave
        const int lq   = lane & 1;
        const int e = perm[e0 + wave * 32 + lrow];
        const int mt = lrow >> 4, lmr = lrow & 15;
        const uint4* xr = (const uint4*)(xbf + (size_t)ecol[e] * NF);
        const nfloat4* ar = (const nfloat4*)(eattr + (size_t)e * NH);
#pragma unroll
        for (int t = 0; t < 8; ++t) {
            const int g = lq + 2 * t;        // 0..15: x half
            const int ks = g >> 2, l4 = g & 3;
            *(uint4*)&At[(((wave * 2 + mt) * 8 + ks) * 64 + l4 * 16 + lmr) * 8] = xr[g];
        }
#pragma unroll
        for (int t = 0; t < 8; ++t) {
            const int g = 16 + lq + 2 * t;   // 16..31: eattr half
            const int ks = g >> 2, l4 = g & 3;
            const int ga = g - 16;
            nfloat4 v0 = __builtin_nontemporal_load(ar + ga * 2);
            nfloat4 v1 = __builtin_nontemporal_load(ar + ga * 2 + 1);
            *(uint4*)&At[(((wave * 2 + mt) * 8 + ks) * 64 + l4 * 16 + lmr) * 8] =
                __builtin_bit_cast(uint4, cvt8(v0, v1));
        }
    }
    lds_fence();   // own-wave staging -> own-wave frag reads

    bf16x8 a1[2][8];
#pragma unroll
    for (int mt = 0; mt < 2; ++mt)
#pragma unroll
        for (int ks = 0; ks < 8; ++ks)
            a1[mt][ks] = load_frag(&At[(((wave * 2 + mt) * 8 + ks) * 64 + lane) * 8]);

    // ---- GEMM1: [32 x 256] @ [256 x 128], each B-frag feeds 2 MFMAs ----
    floatx4 acc1[2][8];
#pragma unroll
    for (int ct = 0; ct < 8; ++ct) {
        floatx4 aA = {0.f, 0.f, 0.f, 0.f};
        floatx4 aB = {0.f, 0.f, 0.f, 0.f};
        const unsigned short* wr = wp1a + (ct * 8 * 64 + lane) * 8;
#pragma unroll
        for (int ks = 0; ks < 8; ++ks) {
            bf16x8 b = load_frag(wr + ks * 512);
            aA = mfma16(a1[0][ks], b, aA);
            aB = mfma16(a1[1][ks], b, aB);
        }
        acc1[0][ct] = aA;
        acc1[1][ct] = aB;
    }

    // ---- bias + ReLU + per-wave LayerNorm (2 row-sets of 16 rows) ----
    float sum_[2][4] = {{0}}, sq_[2][4] = {{0}};
#pragma unroll
    for (int ct = 0; ct < 8; ++ct) {
        const float bb = b1a[ct * 16 + lm];
#pragma unroll
        for (int mt = 0; mt < 2; ++mt)
#pragma unroll
            for (int i = 0; i < 4; ++i) {
                float v = acc1[mt][ct][i] + bb;
                v = fmaxf(v, 0.f);
                acc1[mt][ct][i] = v;
                sum_[mt][i] += v;
                sq_[mt][i]  += v * v;
            }
    }
#pragma unroll
    for (int m = 1; m < 16; m <<= 1) {
#pragma unroll
        for (int mt = 0; mt < 2; ++mt)
#pragma unroll
            for (int i = 0; i < 4; ++i) {
                sum_[mt][i] += __shfl_xor(sum_[mt][i], m, 64);
                sq_[mt][i]  += __shfl_xor(sq_[mt][i],  m, 64);
            }
    }
    float mu[2][4], rs[2][4];
#pragma unroll
    for (int mt = 0; mt < 2; ++mt)
#pragma unroll
        for (int i = 0; i < 4; ++i) {
            mu[mt][i] = sum_[mt][i] * (1.f / NH);
            float var = sq_[mt][i] * (1.f / NH) - mu[mt][i] * mu[mt][i];
            rs[mt][i] = rsqrtf(var + LN_EPS);
        }

    // ---- LN apply -> Ttile (own dead 16KB chunk, row-major [32][136]) ----
    unsigned short* Tt = At + wave * 8192;
#pragma unroll
    for (int ct = 0; ct < 8; ++ct) {
        const int c = ct * 16 + lm;
        const float gg = g1[c], bb = be1[c];
#pragma unroll
        for (int mt = 0; mt < 2; ++mt)
#pragma unroll
            for (int i = 0; i < 4; ++i) {
                float nv = (acc1[mt][ct][i] - mu[mt][i]) * rs[mt][i] * gg + bb;
                Tt[(mt * 16 + lq4 * 4 + i) * 136 + c] =
                    __builtin_bit_cast(unsigned short, (__bf16)nv);
            }
    }
    lds_fence();   // Ttile writes -> a2 reads

    bf16x8 a2[2][4];
#pragma unroll
    for (int mt = 0; mt < 2; ++mt)
#pragma unroll
        for (int ks = 0; ks < 4; ++ks)
            a2[mt][ks] = load_frag(&Tt[(mt * 16 + lm) * 136 + ks * 32 + lq4 * 8]);

    // ---- GEMM2: [32 x 128] @ [128 x 128] -> swizzled f32 accbuf ----
#pragma unroll
    for (int ct = 0; ct < 8; ++ct) {
        floatx4 aA = {0.f, 0.f, 0.f, 0.f};
        floatx4 aB = {0.f, 0.f, 0.f, 0.f};
        const unsigned short* wr = wp1b + (ct * 4 * 64 + lane) * 8;
#pragma unroll
        for (int ks = 0; ks < 4; ++ks) {
            bf16x8 b = load_frag(wr + ks * 512);
            aA = mfma16(a2[0][ks], b, aA);
            aB = mfma16(a2[1][ks], b, aB);
        }
        const int c = ct * 16 + lm;
#pragma unroll
        for (int i = 0; i < 4; ++i) {
            int R = wave * 32 + lq4 * 4 + i;          // mt = 0
            smem[R * 128 + (c ^ ((R & 7) << 2))] = aA[i];
            R += 16;                                   // mt = 1
            smem[R * 128 + (c ^ ((R & 7) << 2))] = aB[i];
        }
    }
    __syncthreads();   // the ONE true cross-wave barrier

    // ---- segmented reduction via row_start ranges (wave-uniform) ----
    {
        const int cc  = threadIdx.x & 127;
        const int par = threadIdx.x >> 7;             // rows interleaved 2-way
        const int r0 = erow[perm[e0]];
        const int r1 = erow[perm[e0 + 127]];
        for (int r = r0 + par; r <= r1; r += 2) {
            int jlo = row_start[r], jhi = row_start[r + 1];
            jlo = jlo > e0 ? jlo : e0;
            jhi = jhi < e0 + 128 ? jhi : e0 + 128;
            if (jlo >= jhi) continue;
            float a = 0.f;
            for (int j = jlo; j < jhi; ++j) {
                const int jj = j - e0;
                a += smem[jj * 128 + (cc ^ ((jj & 7) << 2))];
            }
            atomicAdd(&sums[r * NH + cc], a);
        }
    }
}

// ---------------------------------------------------------------------------
// Node MLP: A = [x[n] | sums[n]/cnt + b1b (cnt>0)], packed weights.
// ---------------------------------------------------------------------------
__global__ __launch_bounds__(256) void node_mlp_kernel(
    const float* __restrict__ x,
    const float* __restrict__ sums, const int* __restrict__ row_start,
    const float* __restrict__ b1b,
    const unsigned short* __restrict__ wp2a, const float* __restrict__ b2a,
    const float* __restrict__ g2, const float* __restrict__ be2,
    const unsigned short* __restrict__ wp2b, const float* __restrict__ b2b,
    float* __restrict__ out)
{
    __shared__ unsigned short Atile[4][16][KA + 8];
    __shared__ unsigned short Ttile[4][16][NH + 8];

    const int wave = threadIdx.x >> 6;
    const int lane = threadIdx.x & 63;
    const int n0 = blockIdx.x * 64 + wave * 16;

    {
        const int lrow = lane >> 2;
        const int lq   = lane & 3;
        int n = n0 + lrow;
        if (n >= NN) n = NN - 1;
        const int cntn = row_start[n + 1] - row_start[n];
        const float inv  = (cntn > 0) ? (1.f / (float)cntn) : 1.f;
        const float addb = (cntn > 0) ? 1.f : 0.f;
        const float4* xr = (const float4*)(x + n * NF);
        const float4* sr = (const float4*)(sums + n * NH);
        const float4* br = (const float4*)b1b;
        unsigned short* Ar = &Atile[wave][lrow][0];
#pragma unroll
        for (int it = 0; it < 8; ++it) {
            int c4 = lq + it * 4;
            float4 v = xr[c4];
            uint2 w;
            w.x = (unsigned)f2bf(v.x) | ((unsigned)f2bf(v.y) << 16);
            w.y = (unsigned)f2bf(v.z) | ((unsigned)f2bf(v.w) << 16);
            *(uint2*)&Ar[c4 * 4] = w;
            float4 v2 = sr[c4];
            float4 bv = br[c4];
            float a0 = v2.x * inv + addb * bv.x;
            float a1 = v2.y * inv + addb * bv.y;
            float a2 = v2.z * inv + addb * bv.z;
            float a3 = v2.w * inv + addb * bv.w;
            uint2 w2;
            w2.x = (unsigned)f2bf(a0) | ((unsigned)f2bf(a1) << 16);
            w2.y = (unsigned)f2bf(a2) | ((unsigned)f2bf(a3) << 16);
            *(uint2*)&Ar[128 + c4 * 4] = w2;
        }
    }
    __syncthreads();

    const int lm  = lane & 15;
    const int lq4 = lane >> 4;

    bf16x8 a1[8];
#pragma unroll
    for (int ks = 0; ks < 8; ++ks)
        a1[ks] = load_frag(&Atile[wave][lm][ks * 32 + lq4 * 8]);

    floatx4 acc1[8];
#pragma unroll
    for (int ct = 0; ct < 8; ++ct) {
        floatx4 acc = {0.f, 0.f, 0.f, 0.f};
        const unsigned short* wr = wp2a + (ct * 8 * 64 + lane) * 8;
#pragma unroll
        for (int ks = 0; ks < 8; ++ks) {
            bf16x8 b = load_frag(wr + ks * 512);
            acc = __builtin_amdgcn_mfma_f32_16x16x32_bf16(a1[ks], b, acc, 0, 0, 0);
        }
        acc1[ct] = acc;
    }

    float sum_[4] = {0, 0, 0, 0}, sq_[4] = {0, 0, 0, 0};
#pragma unroll
    for (int ct = 0; ct < 8; ++ct) {
        const float bb = b2a[ct * 16 + lm];
#pragma unroll
        for (int i = 0; i < 4; ++i) {
            float v = acc1[ct][i] + bb;
            v = fmaxf(v, 0.f);
            acc1[ct][i] = v;
            sum_[i] += v;
            sq_[i]  += v * v;
        }
    }
#pragma unroll
    for (int m = 1; m < 16; m <<= 1) {
#pragma unroll
        for (int i = 0; i < 4; ++i) {
            sum_[i] += __shfl_xor(sum_[i], m, 64);
            sq_[i]  += __shfl_xor(sq_[i],  m, 64);
        }
    }
    float mu[4], rs[4];
#pragma unroll
    for (int i = 0; i < 4; ++i) {
        mu[i] = sum_[i] * (1.f / NH);
        float var = sq_[i] * (1.f / NH) - mu[i] * mu[i];
        rs[i] = rsqrtf(var + LN_EPS);
    }
#pragma unroll
    for (int ct = 0; ct < 8; ++ct) {
        const int c = ct * 16 + lm;
        const float gg = g2[c], bb = be2[c];
#pragma unroll
        for (int i = 0; i < 4; ++i) {
            float nv = (acc1[ct][i] - mu[i]) * rs[i] * gg + bb;
            Ttile[wave][lq4 * 4 + i][c] = f2bf(nv);
        }
    }
    __syncthreads();

    bf16x8 a2[4];
#pragma unroll
    for (int ks = 0; ks < 4; ++ks)
        a2[ks] = load_frag(&Ttile[wave][lm][ks * 32 + lq4 * 8]);

#pragma unroll
    for (int ct = 0; ct < 8; ++ct) {
        floatx4 acc = {0.f, 0.f, 0.f, 0.f};
        const unsigned short* wr = wp2b + (ct * 4 * 64 + lane) * 8;
#pragma unroll
        for (int ks = 0; ks < 4; ++ks) {
            bf16x8 b = load_frag(wr + ks * 512);
            acc = __builtin_amdgcn_mfma_f32_16x16x32_bf16(a2[ks], b, acc, 0, 0, 0);
        }
        const int c = ct * 16 + lm;
        const float bb = b2b[c];
#pragma unroll
        for (int i = 0; i < 4; ++i) {
            int n = n0 + lq4 * 4 + i;
            if (n < NN) out[n * NT + c] = acc[i] + bb;
        }
    }
}

// ---------------------------------------------------------------------------
// Workspace layout (bytes):
//   [0,          5,120,000)  sums      f32 [10000][128]
//   [5,120,000,  5,160,000)  hist      int [10000]
//   [5,160,000,  5,200,000)  cursor    int [10000]
//   [5,200,000,  5,240,064)  row_start int [10001] (padded)
//   [5,240,064,  7,800,064)  perm      int [640000]
//   [7,800,064,  7,865,600)  wp1a      bf16 frag-packed [64][64][8]
//   [7,865,600,  7,898,368)  wp1b      bf16 frag-packed [32][64][8]
//   [7,898,368,  7,963,904)  wp2a      bf16 frag-packed [64][64][8]
//   [7,963,904,  7,996,672)  wp2b      bf16 frag-packed [32][64][8]
//   [7,996,672, 10,556,672)  xbf       bf16 [10000][128]
// ---------------------------------------------------------------------------
extern "C" void kernel_launch(void* const* d_in, const int* in_sizes, int n_in,
                              void* d_out, int out_size, void* d_ws, size_t ws_size,
                              hipStream_t stream) {
    const float* x     = (const float*)d_in[0];
    const int*   eidx  = (const int*)d_in[1];
    const float* eattr = (const float*)d_in[2];
    const float* W1a = (const float*)d_in[3];
    const float* b1a = (const float*)d_in[4];
    const float* g1  = (const float*)d_in[5];
    const float* be1 = (const float*)d_in[6];
    const float* W1b = (const float*)d_in[7];
    const float* b1b = (const float*)d_in[8];
    const float* W2a = (const float*)d_in[9];
    const float* b2a = (const float*)d_in[10];
    const float* g2  = (const float*)d_in[11];
    const float* be2 = (const float*)d_in[12];
    const float* W2b = (const float*)d_in[13];
    const float* b2b = (const float*)d_in[14];

    char* ws = (char*)d_ws;
    float* sums      = (float*)ws;
    int*   hist      = (int*)(ws + 5120000);
    int*   cursor    = (int*)(ws + 5160000);
    int*   row_start = (int*)(ws + 5200000);
    int*   perm      = (int*)(ws + 5240064);
    unsigned short* wp1a = (unsigned short*)(ws + 7800064);
    unsigned short* wp1b = (unsigned short*)(ws + 7865600);
    unsigned short* wp2a = (unsigned short*)(ws + 7898368);
    unsigned short* wp2b = (unsigned short*)(ws + 7963904);
    unsigned short* xbf  = (unsigned short*)(ws + 7996672);

    const int* erow = eidx;
    const int* ecol = eidx + NE;

    (void)hipMemsetAsync(ws, 0, 5160000, stream);   // zero sums + hist
    prep_kernel<<<640, 256, 0, stream>>>(x, W1a, W1b, W2a, W2b,
                                         wp1a, wp1b, wp2a, wp2b, xbf);
    hist_kernel<<<(NE + 255) / 256, 256, 0, stream>>>(erow, hist);
    scan_kernel<<<1, 256, 0, stream>>>(hist, row_start, cursor);
    scatter_kernel<<<(NE + 255) / 256, 256, 0, stream>>>(erow, cursor, perm);
    edge_mlp_kernel<<<NE / 128, 256, 0, stream>>>(xbf, erow, ecol, eattr, perm,
                                                  wp1a, b1a, g1, be1, wp1b,
                                                  row_start, sums);
    node_mlp_kernel<<<(NN + 63) / 64, 256, 0, stream>>>(x, sums, row_start, b1b,
                                                        wp2a, b2a, g2, be2, wp2b, b2b,
                                                        (float*)d_out);
}

// Round 7
// 695.014 us; speedup vs baseline: 2.8757x; 1.0755x over previous
//
#include <hip/hip_runtime.h>
#include <hip/hip_bf16.h>

#define NN 10000
#define NE 640000
#define NF 128
#define NH 128
#define NT 128
#define KA 256   // NF + NH
#define LN_EPS 1e-5f

typedef __bf16 bf16x8 __attribute__((ext_vector_type(8)));
typedef float floatx4 __attribute__((ext_vector_type(4)));
typedef float nfloat4 __attribute__((ext_vector_type(4)));

__device__ inline unsigned short f2bf(float f) {
    unsigned int u = __float_as_uint(f);
    u += 0x7FFFu + ((u >> 16) & 1u);   // round-to-nearest-even
    return (unsigned short)(u >> 16);
}

__device__ inline bf16x8 load_frag(const unsigned short* p) {
    uint4 u = *(const uint4*)p;
    return __builtin_bit_cast(bf16x8, u);
}

__device__ inline floatx4 mfma16(bf16x8 a, bf16x8 b, floatx4 c) {
    return __builtin_amdgcn_mfma_f32_16x16x32_bf16(a, b, c, 0, 0, 0);
}

// native casts -> v_cvt_pk_bf16_f32 (RTNE), 2 floats/instr
__device__ inline bf16x8 cvt8(nfloat4 v0, nfloat4 v1) {
    bf16x8 r;
    r[0] = (__bf16)v0.x; r[1] = (__bf16)v0.y; r[2] = (__bf16)v0.z; r[3] = (__bf16)v0.w;
    r[4] = (__bf16)v1.x; r[5] = (__bf16)v1.y; r[6] = (__bf16)v1.z; r[7] = (__bf16)v1.w;
    return r;
}

// wave-local LDS ordering fence; sched_barrier stops hipcc hoisting past it
__device__ inline void lds_fence() {
    asm volatile("s_waitcnt lgkmcnt(0)" ::: "memory");
    __builtin_amdgcn_sched_barrier(0);
}

// ---------------------------------------------------------------------------
// Prep: pack weights f32 [K][N] -> bf16 MFMA-fragment order, and x -> bf16.
// Fragment f=(ct*nks+ks): 64 lanes x 8 elems contiguous (1KB). Lane l holds
// B[k = ks*32 + (l>>4)*8 + j][n = ct*16 + (l&15)].
// ---------------------------------------------------------------------------
__global__ __launch_bounds__(256) void prep_kernel(
    const float* __restrict__ x,
    const float* __restrict__ W1a, const float* __restrict__ W1b,
    const float* __restrict__ W2a, const float* __restrict__ W2b,
    unsigned short* __restrict__ wp1a, unsigned short* __restrict__ wp1b,
    unsigned short* __restrict__ wp2a, unsigned short* __restrict__ wp2b,
    unsigned short* __restrict__ xbf)
{
    const int tid = blockIdx.x * 256 + threadIdx.x;
    const int nth = gridDim.x * 256;

    // x (f32 [10000][128]) -> xbf (bf16), 160000 x 16B
    const nfloat4* xs = (const nfloat4*)x;
    uint4* xd = (uint4*)xbf;
    for (int i = tid; i < 160000; i += nth)
        xd[i] = __builtin_bit_cast(uint4, cvt8(xs[2 * i], xs[2 * i + 1]));

    if (tid < 12288) {
        const float* src; unsigned short* dst; int t, nks;
        if (tid < 4096)       { src = W1a; dst = wp1a; t = tid;         nks = 8; }
        else if (tid < 6144)  { src = W1b; dst = wp1b; t = tid - 4096;  nks = 4; }
        else if (tid < 10240) { src = W2a; dst = wp2a; t = tid - 6144;  nks = 8; }
        else                  { src = W2b; dst = wp2b; t = tid - 10240; nks = 4; }
        const int f = t >> 6, l = t & 63;
        const int ct = f / nks, ks = f - ct * nks;
        const int n  = ct * 16 + (l & 15);
        const int k0 = ks * 32 + (l >> 4) * 8;
        unsigned short tmp[8];
#pragma unroll
        for (int j = 0; j < 8; ++j)
            tmp[j] = f2bf(src[(k0 + j) * 128 + n]);
        *(uint4*)&dst[t * 8] = *(const uint4*)tmp;
    }
}

// ---------------------------------------------------------------------------
// Counting sort by target row: hist -> scan -> scatter.
// ---------------------------------------------------------------------------
__global__ __launch_bounds__(256) void hist_kernel(
    const int* __restrict__ row, int* __restrict__ hist)
{
    int e = blockIdx.x * 256 + threadIdx.x;
    if (e < NE) atomicAdd(&hist[row[e]], 1);
}

__global__ __launch_bounds__(256) void scan_kernel(
    const int* __restrict__ hist, int* __restrict__ row_start,
    int* __restrict__ cursor)
{
    __shared__ int partials[256];
    const int t = threadIdx.x;
    const int base = t * 40;                  // 256*40 = 10240 >= NN
    int s = 0;
    for (int i = 0; i < 40; ++i) {
        int b = base + i;
        if (b < NN) s += hist[b];
    }
    partials[t] = s;
    __syncthreads();
    int pre = 0;
    for (int i = 0; i < t; ++i) pre += partials[i];
    int run = pre;
    for (int i = 0; i < 40; ++i) {
        int b = base + i;
        if (b < NN) {
            row_start[b] = run;
            cursor[b] = run;
            run += hist[b];
        }
    }
    if (t == 255) row_start[NN] = NE;
}

__global__ __launch_bounds__(256) void scatter_kernel(
    const int* __restrict__ row, int* __restrict__ cursor,
    int* __restrict__ perm)
{
    int e = blockIdx.x * 256 + threadIdx.x;
    if (e < NE) {
        int p = atomicAdd(&cursor[row[e]], 1);
        perm[p] = e;
    }
}

// ---------------------------------------------------------------------------
// Edge MLP "no-GEMM2": since Σ_e(h1_e @ W1b + b1b) = (Σ_e h1_e)@W1b + cnt*b1b,
// the per-edge GEMM2 commutes with the segment-sum and moves to the node
// kernel. Edge kernel = R0 schedule (one 64-edge tile/block, retire fast):
// stage -> GEMM1 -> bias/ReLU/LN -> f32 h1 straight into the aliased accbuf
// -> ONE barrier -> segmented sum -> atomicAdd into H[r] (f32 [10000][128]).
// Removes per tile: Ttile bf16 roundtrip, a2 reads, 32 MFMAs, 32KB L2 B-loads.
// LDS 34KB (R3-proven alias: Atile shorts [64][264] == accbuf f32 [64][132])
// -> 4 blocks/CU. bf16 quantization now happens on the per-row MEAN (node),
// not per edge -> numerics same or better.
// ---------------------------------------------------------------------------
__global__ __launch_bounds__(256, 4) void edge_mlp_kernel(
    const unsigned short* __restrict__ xbf,
    const int* __restrict__ erow, const int* __restrict__ ecol,
    const float* __restrict__ eattr,
    const int* __restrict__ perm,
    const unsigned short* __restrict__ wp1a, const float* __restrict__ b1a,
    const float* __restrict__ g1, const float* __restrict__ be1,
    float* __restrict__ H)
{
    __shared__ __align__(16) float smem[64 * 132];   // 33792 B, aliased views
    __shared__ int rows_s[64];

    const int wave = threadIdx.x >> 6;
    const int lane = threadIdx.x & 63;
    const int lm   = lane & 15;
    const int lq4  = lane >> 4;
    const int e0   = blockIdx.x * 64;

    unsigned short* At = (unsigned short*)smem;      // [64][264] shorts view

    if (threadIdx.x < 64)
        rows_s[threadIdx.x] = erow[perm[e0 + threadIdx.x]];

    // ---- stage A = [xbf[col] | cvt(eattr)] bf16 into own wave's rows ----
    {
        const int lrow = lane >> 2;          // 0..15: edge slot within wave
        const int lq   = lane & 3;
        const int e = perm[e0 + wave * 16 + lrow];
        const int scol = ecol[e];
        const uint4* xr = (const uint4*)(xbf + (size_t)scol * NF);
        const nfloat4* ar = (const nfloat4*)(eattr + (size_t)e * NH);
        unsigned short* Ar = At + (wave * 16 + lrow) * 264;
#pragma unroll
        for (int it = 0; it < 4; ++it) {
            const int g = lq + it * 4;       // 16B granule 0..15
            *(uint4*)&Ar[g * 8] = xr[g];
        }
#pragma unroll
        for (int it = 0; it < 4; ++it) {
            const int g = lq + it * 4;
            nfloat4 v0 = __builtin_nontemporal_load(ar + g * 2);
            nfloat4 v1 = __builtin_nontemporal_load(ar + g * 2 + 1);
            *(uint4*)&Ar[128 + g * 8] = __builtin_bit_cast(uint4, cvt8(v0, v1));
        }
    }
    lds_fence();   // own-wave staging writes -> own-wave frag reads

    bf16x8 a1[8];
#pragma unroll
    for (int ks = 0; ks < 8; ++ks)
        a1[ks] = load_frag(&At[(wave * 16 + lm) * 264 + ks * 32 + lq4 * 8]);

    // ---- GEMM1: [16 x 256] @ [256 x 128] ----
    floatx4 acc1[8];
#pragma unroll
    for (int ct = 0; ct < 8; ++ct) {
        floatx4 acc = {0.f, 0.f, 0.f, 0.f};
        const unsigned short* wr = wp1a + (ct * 8 * 64 + lane) * 8;
#pragma unroll
        for (int ks = 0; ks < 8; ++ks) {
            bf16x8 b = load_frag(wr + ks * 512);
            acc = mfma16(a1[ks], b, acc);
        }
        acc1[ct] = acc;
    }

    // ---- bias + ReLU + per-wave LayerNorm stats ----
    float sum_[4] = {0, 0, 0, 0}, sq_[4] = {0, 0, 0, 0};
#pragma unroll
    for (int ct = 0; ct < 8; ++ct) {
        const float bb = b1a[ct * 16 + lm];
#pragma unroll
        for (int i = 0; i < 4; ++i) {
            float v = acc1[ct][i] + bb;
            v = fmaxf(v, 0.f);
            acc1[ct][i] = v;
            sum_[i] += v;
            sq_[i]  += v * v;
        }
    }
#pragma unroll
    for (int m = 1; m < 16; m <<= 1) {
#pragma unroll
        for (int i = 0; i < 4; ++i) {
            sum_[i] += __shfl_xor(sum_[i], m, 64);
            sq_[i]  += __shfl_xor(sq_[i],  m, 64);
        }
    }
    float mu[4], rs[4];
#pragma unroll
    for (int i = 0; i < 4; ++i) {
        mu[i] = sum_[i] * (1.f / NH);
        float var = sq_[i] * (1.f / NH) - mu[i] * mu[i];
        rs[i] = rsqrtf(var + LN_EPS);
    }

    // ---- LN apply -> f32 h1 straight into accbuf (aliases own dead Atile
    // rows; stores data-depend on a1 reads so ordering is guaranteed) ----
#pragma unroll
    for (int ct = 0; ct < 8; ++ct) {
        const int c = ct * 16 + lm;
        const float gg = g1[c], bb = be1[c];
#pragma unroll
        for (int i = 0; i < 4; ++i) {
            const int r = wave * 16 + lq4 * 4 + i;
            smem[r * 132 + c] = (acc1[ct][i] - mu[i]) * rs[i] * gg + bb;
        }
    }
    __syncthreads();   // the ONE true cross-wave barrier

    // ---- segmented reduction over the block's 64 sorted edges -> H ----
    {
        const int t = threadIdx.x;
        const int cc = t & 127;
        const int jb = (t >> 7) * 32;
        float a = 0.f;
        int cur = rows_s[jb];
#pragma unroll 4
        for (int j = jb; j < jb + 32; ++j) {
            a += smem[j * 132 + cc];
            int nxt = (j + 1 < jb + 32) ? rows_s[j + 1] : -1;
            if (nxt != cur) {
                atomicAdd(&H[cur * NH + cc], a);
                a = 0.f;
                cur = nxt;
            }
        }
    }
}

// ---------------------------------------------------------------------------
// Node MLP: agg = (H[n]/cnt)@W1b + b1b (cnt>0) computed HERE (GEMM0, moved
// from the edge kernel by linearity), then A = [x | agg] -> existing MLP2.
// ---------------------------------------------------------------------------
__global__ __launch_bounds__(256) void node_mlp_kernel(
    const unsigned short* __restrict__ xbf,
    const float* __restrict__ H, const int* __restrict__ row_start,
    const float* __restrict__ b1b, const unsigned short* __restrict__ wp1b,
    const unsigned short* __restrict__ wp2a, const float* __restrict__ b2a,
    const float* __restrict__ g2, const float* __restrict__ be2,
    const unsigned short* __restrict__ wp2b, const float* __restrict__ b2b,
    float* __restrict__ out)
{
    __shared__ unsigned short Atile[4][16][KA + 8];
    __shared__ unsigned short Ttile[4][16][NH + 8];   // Hm frags, later LN out
    __shared__ float addb_s[4][16];

    const int wave = threadIdx.x >> 6;
    const int lane = threadIdx.x & 63;
    const int lm   = lane & 15;
    const int lq4  = lane >> 4;
    const int n0 = blockIdx.x * 64 + wave * 16;

    // ---- stage x -> Atile[0..127], Hm = H/cnt (bf16) -> Ttile ----
    {
        const int lrow = lane >> 2;
        const int lq   = lane & 3;
        int n = n0 + lrow;
        if (n >= NN) n = NN - 1;
        const int cntn = row_start[n + 1] - row_start[n];
        const float inv  = (cntn > 0) ? (1.f / (float)cntn) : 1.f;
        if (lq == 0) addb_s[wave][lrow] = (cntn > 0) ? 1.f : 0.f;
        const uint4* xr = (const uint4*)(xbf + (size_t)n * NF);
        const nfloat4* hr = (const nfloat4*)(H + (size_t)n * NH);
        unsigned short* Ar = &Atile[wave][lrow][0];
        unsigned short* Tr = &Ttile[wave][lrow][0];
#pragma unroll
        for (int it = 0; it < 4; ++it) {
            const int g = lq + it * 4;
            *(uint4*)&Ar[g * 8] = xr[g];
            nfloat4 v0 = hr[g * 2], v1 = hr[g * 2 + 1];
            nfloat4 u0, u1;
            u0.x = v0.x * inv; u0.y = v0.y * inv; u0.z = v0.z * inv; u0.w = v0.w * inv;
            u1.x = v1.x * inv; u1.y = v1.y * inv; u1.z = v1.z * inv; u1.w = v1.w * inv;
            *(uint4*)&Tr[g * 8] = __builtin_bit_cast(uint4, cvt8(u0, u1));
        }
    }
    __syncthreads();

    // ---- GEMM0: agg = Hm @ W1b + addb*b1b -> bf16 Atile[128..255] ----
    {
        bf16x8 ah[4];
#pragma unroll
        for (int ks = 0; ks < 4; ++ks)
            ah[ks] = load_frag(&Ttile[wave][lm][ks * 32 + lq4 * 8]);
#pragma unroll
        for (int ct = 0; ct < 8; ++ct) {
            floatx4 acc = {0.f, 0.f, 0.f, 0.f};
            const unsigned short* wr = wp1b + (ct * 4 * 64 + lane) * 8;
#pragma unroll
            for (int ks = 0; ks < 4; ++ks) {
                bf16x8 b = load_frag(wr + ks * 512);
                acc = mfma16(ah[ks], b, acc);
            }
            const int c = ct * 16 + lm;
            const float bb = b1b[c];
#pragma unroll
            for (int i = 0; i < 4; ++i) {
                float av = acc[i] + addb_s[wave][lq4 * 4 + i] * bb;
                Atile[wave][lq4 * 4 + i][128 + c] = f2bf(av);
            }
        }
    }
    lds_fence();   // own-wave agg writes -> own-wave a1 reads

    bf16x8 a1[8];
#pragma unroll
    for (int ks = 0; ks < 8; ++ks)
        a1[ks] = load_frag(&Atile[wave][lm][ks * 32 + lq4 * 8]);

    floatx4 acc1[8];
#pragma unroll
    for (int ct = 0; ct < 8; ++ct) {
        floatx4 acc = {0.f, 0.f, 0.f, 0.f};
        const unsigned short* wr = wp2a + (ct * 8 * 64 + lane) * 8;
#pragma unroll
        for (int ks = 0; ks < 8; ++ks) {
            bf16x8 b = load_frag(wr + ks * 512);
            acc = mfma16(a1[ks], b, acc);
        }
        acc1[ct] = acc;
    }

    float sum_[4] = {0, 0, 0, 0}, sq_[4] = {0, 0, 0, 0};
#pragma unroll
    for (int ct = 0; ct < 8; ++ct) {
        const float bb = b2a[ct * 16 + lm];
#pragma unroll
        for (int i = 0; i < 4; ++i) {
            float v = acc1[ct][i] + bb;
            v = fmaxf(v, 0.f);
            acc1[ct][i] = v;
            sum_[i] += v;
            sq_[i]  += v * v;
        }
    }
#pragma unroll
    for (int m = 1; m < 16; m <<= 1) {
#pragma unroll
        for (int i = 0; i < 4; ++i) {
            sum_[i] += __shfl_xor(sum_[i], m, 64);
            sq_[i]  += __shfl_xor(sq_[i],  m, 64);
        }
    }
    float mu[4], rs[4];
#pragma unroll
    for (int i = 0; i < 4; ++i) {
        mu[i] = sum_[i] * (1.f / NH);
        float var = sq_[i] * (1.f / NH) - mu[i] * mu[i];
        rs[i] = rsqrtf(var + LN_EPS);
    }
#pragma unroll
    for (int ct = 0; ct < 8; ++ct) {
        const int c = ct * 16 + lm;
        const float gg = g2[c], bb = be2[c];
#pragma unroll
        for (int i = 0; i < 4; ++i) {
            float nv = (acc1[ct][i] - mu[i]) * rs[i] * gg + bb;
            Ttile[wave][lq4 * 4 + i][c] = f2bf(nv);
        }
    }
    __syncthreads();

    bf16x8 a2[4];
#pragma unroll
    for (int ks = 0; ks < 4; ++ks)
        a2[ks] = load_frag(&Ttile[wave][lm][ks * 32 + lq4 * 8]);

#pragma unroll
    for (int ct = 0; ct < 8; ++ct) {
        floatx4 acc = {0.f, 0.f, 0.f, 0.f};
        const unsigned short* wr = wp2b + (ct * 4 * 64 + lane) * 8;
#pragma unroll
        for (int ks = 0; ks < 4; ++ks) {
            bf16x8 b = load_frag(wr + ks * 512);
            acc = mfma16(a2[ks], b, acc);
        }
        const int c = ct * 16 + lm;
        const float bb = b2b[c];
#pragma unroll
        for (int i = 0; i < 4; ++i) {
            int n = n0 + lq4 * 4 + i;
            if (n < NN) out[n * NT + c] = acc[i] + bb;
        }
    }
}

// ---------------------------------------------------------------------------
// Workspace layout (bytes):
//   [0,          5,120,000)  H (sums)  f32 [10000][128]
//   [5,120,000,  5,160,000)  hist      int [10000]
//   [5,160,000,  5,200,000)  cursor    int [10000]
//   [5,200,000,  5,240,064)  row_start int [10001] (padded)
//   [5,240,064,  7,800,064)  perm      int [640000]
//   [7,800,064,  7,865,600)  wp1a      bf16 frag-packed [64][64][8]
//   [7,865,600,  7,898,368)  wp1b      bf16 frag-packed [32][64][8]
//   [7,898,368,  7,963,904)  wp2a      bf16 frag-packed [64][64][8]
//   [7,963,904,  7,996,672)  wp2b      bf16 frag-packed [32][64][8]
//   [7,996,672, 10,556,672)  xbf       bf16 [10000][128]
// ---------------------------------------------------------------------------
extern "C" void kernel_launch(void* const* d_in, const int* in_sizes, int n_in,
                              void* d_out, int out_size, void* d_ws, size_t ws_size,
                              hipStream_t stream) {
    const float* x     = (const float*)d_in[0];
    const int*   eidx  = (const int*)d_in[1];
    const float* eattr = (const float*)d_in[2];
    const float* W1a = (const float*)d_in[3];
    const float* b1a = (const float*)d_in[4];
    const float* g1  = (const float*)d_in[5];
    const float* be1 = (const float*)d_in[6];
    const float* W1b = (const float*)d_in[7];
    const float* b1b = (const float*)d_in[8];
    const float* W2a = (const float*)d_in[9];
    const float* b2a = (const float*)d_in[10];
    const float* g2  = (const float*)d_in[11];
    const float* be2 = (const float*)d_in[12];
    const float* W2b = (const float*)d_in[13];
    const float* b2b = (const float*)d_in[14];

    char* ws = (char*)d_ws;
    float* H         = (float*)ws;
    int*   hist      = (int*)(ws + 5120000);
    int*   cursor    = (int*)(ws + 5160000);
    int*   row_start = (int*)(ws + 5200000);
    int*   perm      = (int*)(ws + 5240064);
    unsigned short* wp1a = (unsigned short*)(ws + 7800064);
    unsigned short* wp1b = (unsigned short*)(ws + 7865600);
    unsigned short* wp2a = (unsigned short*)(ws + 7898368);
    unsigned short* wp2b = (unsigned short*)(ws + 7963904);
    unsigned short* xbf  = (unsigned short*)(ws + 7996672);

    const int* erow = eidx;
    const int* ecol = eidx + NE;

    (void)hipMemsetAsync(ws, 0, 5160000, stream);   // zero H + hist
    prep_kernel<<<640, 256, 0, stream>>>(x, W1a, W1b, W2a, W2b,
                                         wp1a, wp1b, wp2a, wp2b, xbf);
    hist_kernel<<<(NE + 255) / 256, 256, 0, stream>>>(erow, hist);
    scan_kernel<<<1, 256, 0, stream>>>(hist, row_start, cursor);
    scatter_kernel<<<(NE + 255) / 256, 256, 0, stream>>>(erow, cursor, perm);
    edge_mlp_kernel<<<NE / 64, 256, 0, stream>>>(xbf, erow, ecol, eattr, perm,
                                                 wp1a, b1a, g1, be1, H);
    node_mlp_kernel<<<(NN + 63) / 64, 256, 0, stream>>>(xbf, H, row_start,
                                                        b1b, wp1b,
                                                        wp2a, b2a, g2, be2,
                                                        wp2b, b2b,
                                                        (float*)d_out);
}

// Round 8
// 687.414 us; speedup vs baseline: 2.9075x; 1.0111x over previous
//
#include <hip/hip_runtime.h>
#include <hip/hip_bf16.h>

#define NN 10000
#define NE 640000
#define NF 128
#define NH 128
#define NT 128
#define KA 256   // NF + NH
#define LN_EPS 1e-5f

typedef __bf16 bf16x8 __attribute__((ext_vector_type(8)));
typedef float floatx4 __attribute__((ext_vector_type(4)));
typedef float nfloat4 __attribute__((ext_vector_type(4)));

__device__ inline unsigned short f2bf(float f) {
    unsigned int u = __float_as_uint(f);
    u += 0x7FFFu + ((u >> 16) & 1u);   // round-to-nearest-even
    return (unsigned short)(u >> 16);
}

__device__ inline bf16x8 load_frag(const unsigned short* p) {
    uint4 u = *(const uint4*)p;
    return __builtin_bit_cast(bf16x8, u);
}

__device__ inline floatx4 mfma16(bf16x8 a, bf16x8 b, floatx4 c) {
    return __builtin_amdgcn_mfma_f32_16x16x32_bf16(a, b, c, 0, 0, 0);
}

// native casts -> v_cvt_pk_bf16_f32 (RTNE), 2 floats/instr
__device__ inline bf16x8 cvt8(nfloat4 v0, nfloat4 v1) {
    bf16x8 r;
    r[0] = (__bf16)v0.x; r[1] = (__bf16)v0.y; r[2] = (__bf16)v0.z; r[3] = (__bf16)v0.w;
    r[4] = (__bf16)v1.x; r[5] = (__bf16)v1.y; r[6] = (__bf16)v1.z; r[7] = (__bf16)v1.w;
    return r;
}

// wave-local LDS ordering fence; sched_barrier stops hipcc hoisting past it
__device__ inline void lds_fence() {
    asm volatile("s_waitcnt lgkmcnt(0)" ::: "memory");
    __builtin_amdgcn_sched_barrier(0);
}

// ---------------------------------------------------------------------------
// Prep (+ fused histogram): pack weights f32 [K][N] -> bf16 MFMA-fragment
// order, x -> bf16, and build the row histogram (was its own dispatch).
// Fragment f=(ct*nks+ks): 64 lanes x 8 elems contiguous (1KB). Lane l holds
// B[k = ks*32 + (l>>4)*8 + j][n = ct*16 + (l&15)].
// ---------------------------------------------------------------------------
__global__ __launch_bounds__(256) void prep_kernel(
    const float* __restrict__ x,
    const int* __restrict__ erow,
    const float* __restrict__ W1a, const float* __restrict__ W1b,
    const float* __restrict__ W2a, const float* __restrict__ W2b,
    unsigned short* __restrict__ wp1a, unsigned short* __restrict__ wp1b,
    unsigned short* __restrict__ wp2a, unsigned short* __restrict__ wp2b,
    unsigned short* __restrict__ xbf, int* __restrict__ hist)
{
    const int tid = blockIdx.x * 256 + threadIdx.x;
    const int nth = gridDim.x * 256;

    // histogram of target rows (fused: overlaps the streaming below)
    for (int e = tid; e < NE; e += nth)
        atomicAdd(&hist[erow[e]], 1);

    // x (f32 [10000][128]) -> xbf (bf16), 160000 x 16B
    const nfloat4* xs = (const nfloat4*)x;
    uint4* xd = (uint4*)xbf;
    for (int i = tid; i < 160000; i += nth)
        xd[i] = __builtin_bit_cast(uint4, cvt8(xs[2 * i], xs[2 * i + 1]));

    if (tid < 12288) {
        const float* src; unsigned short* dst; int t, nks;
        if (tid < 4096)       { src = W1a; dst = wp1a; t = tid;         nks = 8; }
        else if (tid < 6144)  { src = W1b; dst = wp1b; t = tid - 4096;  nks = 4; }
        else if (tid < 10240) { src = W2a; dst = wp2a; t = tid - 6144;  nks = 8; }
        else                  { src = W2b; dst = wp2b; t = tid - 10240; nks = 4; }
        const int f = t >> 6, l = t & 63;
        const int ct = f / nks, ks = f - ct * nks;
        const int n  = ct * 16 + (l & 15);
        const int k0 = ks * 32 + (l >> 4) * 8;
        unsigned short tmp[8];
#pragma unroll
        for (int j = 0; j < 8; ++j)
            tmp[j] = f2bf(src[(k0 + j) * 128 + n]);
        *(uint4*)&dst[t * 8] = *(const uint4*)tmp;
    }
}

// ---------------------------------------------------------------------------
// Counting sort by target row: scan -> scatter.
// ---------------------------------------------------------------------------
__global__ __launch_bounds__(256) void scan_kernel(
    const int* __restrict__ hist, int* __restrict__ row_start,
    int* __restrict__ cursor)
{
    __shared__ int partials[256];
    const int t = threadIdx.x;
    const int base = t * 40;                  // 256*40 = 10240 >= NN
    int s = 0;
    for (int i = 0; i < 40; ++i) {
        int b = base + i;
        if (b < NN) s += hist[b];
    }
    partials[t] = s;
    __syncthreads();
    int pre = 0;
    for (int i = 0; i < t; ++i) pre += partials[i];
    int run = pre;
    for (int i = 0; i < 40; ++i) {
        int b = base + i;
        if (b < NN) {
            row_start[b] = run;
            cursor[b] = run;
            run += hist[b];
        }
    }
    if (t == 255) row_start[NN] = NE;
}

__global__ __launch_bounds__(256) void scatter_kernel(
    const int* __restrict__ row, int* __restrict__ cursor,
    int* __restrict__ perm)
{
    int e = blockIdx.x * 256 + threadIdx.x;
    if (e < NE) {
        int p = atomicAdd(&cursor[row[e]], 1);
        perm[p] = e;
    }
}

// ---------------------------------------------------------------------------
// Edge MLP "no-GEMM2" (R7, validated): Σ_e(h1_e @ W1b + b1b) =
// (Σ_e h1_e)@W1b + cnt*b1b, so GEMM2 lives in the node kernel. Here:
// stage -> GEMM1 -> bias/ReLU/LN -> f32 h1 into aliased accbuf -> ONE
// barrier -> segmented sum -> atomicAdd into H. LDS 34KB -> 4 blocks/CU.
// ---------------------------------------------------------------------------
__global__ __launch_bounds__(256, 4) void edge_mlp_kernel(
    const unsigned short* __restrict__ xbf,
    const int* __restrict__ erow, const int* __restrict__ ecol,
    const float* __restrict__ eattr,
    const int* __restrict__ perm,
    const unsigned short* __restrict__ wp1a, const float* __restrict__ b1a,
    const float* __restrict__ g1, const float* __restrict__ be1,
    float* __restrict__ H)
{
    __shared__ __align__(16) float smem[64 * 132];   // 33792 B, aliased views
    __shared__ int rows_s[64];

    const int wave = threadIdx.x >> 6;
    const int lane = threadIdx.x & 63;
    const int lm   = lane & 15;
    const int lq4  = lane >> 4;
    const int e0   = blockIdx.x * 64;

    unsigned short* At = (unsigned short*)smem;      // [64][264] shorts view

    if (threadIdx.x < 64)
        rows_s[threadIdx.x] = erow[perm[e0 + threadIdx.x]];

    // ---- stage A = [xbf[col] | cvt(eattr)] bf16 into own wave's rows ----
    {
        const int lrow = lane >> 2;          // 0..15: edge slot within wave
        const int lq   = lane & 3;
        const int e = perm[e0 + wave * 16 + lrow];
        const int scol = ecol[e];
        const uint4* xr = (const uint4*)(xbf + (size_t)scol * NF);
        const nfloat4* ar = (const nfloat4*)(eattr + (size_t)e * NH);
        unsigned short* Ar = At + (wave * 16 + lrow) * 264;
#pragma unroll
        for (int it = 0; it < 4; ++it) {
            const int g = lq + it * 4;       // 16B granule 0..15
            *(uint4*)&Ar[g * 8] = xr[g];
        }
#pragma unroll
        for (int it = 0; it < 4; ++it) {
            const int g = lq + it * 4;
            nfloat4 v0 = __builtin_nontemporal_load(ar + g * 2);
            nfloat4 v1 = __builtin_nontemporal_load(ar + g * 2 + 1);
            *(uint4*)&Ar[128 + g * 8] = __builtin_bit_cast(uint4, cvt8(v0, v1));
        }
    }
    lds_fence();   // own-wave staging writes -> own-wave frag reads

    bf16x8 a1[8];
#pragma unroll
    for (int ks = 0; ks < 8; ++ks)
        a1[ks] = load_frag(&At[(wave * 16 + lm) * 264 + ks * 32 + lq4 * 8]);

    // ---- GEMM1: [16 x 256] @ [256 x 128] ----
    floatx4 acc1[8];
#pragma unroll
    for (int ct = 0; ct < 8; ++ct) {
        floatx4 acc = {0.f, 0.f, 0.f, 0.f};
        const unsigned short* wr = wp1a + (ct * 8 * 64 + lane) * 8;
#pragma unroll
        for (int ks = 0; ks < 8; ++ks) {
            bf16x8 b = load_frag(wr + ks * 512);
            acc = mfma16(a1[ks], b, acc);
        }
        acc1[ct] = acc;
    }

    // ---- bias + ReLU + per-wave LayerNorm stats ----
    float sum_[4] = {0, 0, 0, 0}, sq_[4] = {0, 0, 0, 0};
#pragma unroll
    for (int ct = 0; ct < 8; ++ct) {
        const float bb = b1a[ct * 16 + lm];
#pragma unroll
        for (int i = 0; i < 4; ++i) {
            float v = acc1[ct][i] + bb;
            v = fmaxf(v, 0.f);
            acc1[ct][i] = v;
            sum_[i] += v;
            sq_[i]  += v * v;
        }
    }
#pragma unroll
    for (int m = 1; m < 16; m <<= 1) {
#pragma unroll
        for (int i = 0; i < 4; ++i) {
            sum_[i] += __shfl_xor(sum_[i], m, 64);
            sq_[i]  += __shfl_xor(sq_[i],  m, 64);
        }
    }
    float mu[4], rs[4];
#pragma unroll
    for (int i = 0; i < 4; ++i) {
        mu[i] = sum_[i] * (1.f / NH);
        float var = sq_[i] * (1.f / NH) - mu[i] * mu[i];
        rs[i] = rsqrtf(var + LN_EPS);
    }

    // ---- LN apply -> f32 h1 straight into accbuf (aliases dead Atile) ----
#pragma unroll
    for (int ct = 0; ct < 8; ++ct) {
        const int c = ct * 16 + lm;
        const float gg = g1[c], bb = be1[c];
#pragma unroll
        for (int i = 0; i < 4; ++i) {
            const int r = wave * 16 + lq4 * 4 + i;
            smem[r * 132 + c] = (acc1[ct][i] - mu[i]) * rs[i] * gg + bb;
        }
    }
    __syncthreads();   // the ONE true cross-wave barrier

    // ---- segmented reduction over the block's 64 sorted edges -> H ----
    {
        const int t = threadIdx.x;
        const int cc = t & 127;
        const int jb = (t >> 7) * 32;
        float a = 0.f;
        int cur = rows_s[jb];
#pragma unroll 4
        for (int j = jb; j < jb + 32; ++j) {
            a += smem[j * 132 + cc];
            int nxt = (j + 1 < jb + 32) ? rows_s[j + 1] : -1;
            if (nxt != cur) {
                atomicAdd(&H[cur * NH + cc], a);
                a = 0.f;
                cur = nxt;
            }
        }
    }
}

// ---------------------------------------------------------------------------
// Node MLP, single-wave blocks: 64 threads = 1 wave = 16 nodes, grid 625
// (was 157x256 = 0.6 blocks/CU, ~40% of the GPU idle). All phases are
// wave-private -> zero __syncthreads, lgkmcnt fences only; LDS 13KB.
// agg = (H[n]/cnt)@W1b + b1b (cnt>0) computed here (GEMM0, by linearity),
// then A = [x | agg] -> MLP2.
// ---------------------------------------------------------------------------
__global__ __launch_bounds__(64) void node_mlp_kernel(
    const unsigned short* __restrict__ xbf,
    const float* __restrict__ H, const int* __restrict__ row_start,
    const float* __restrict__ b1b, const unsigned short* __restrict__ wp1b,
    const unsigned short* __restrict__ wp2a, const float* __restrict__ b2a,
    const float* __restrict__ g2, const float* __restrict__ be2,
    const unsigned short* __restrict__ wp2b, const float* __restrict__ b2b,
    float* __restrict__ out)
{
    __shared__ unsigned short Atile[16][KA + 8];
    __shared__ unsigned short Ttile[16][NH + 8];   // Hm frags, later LN out
    __shared__ float addb_s[16];

    const int lane = threadIdx.x;        // 0..63, one wave
    const int lm   = lane & 15;
    const int lq4  = lane >> 4;
    const int n0   = blockIdx.x * 16;

    // ---- stage x -> Atile[0..127], Hm = H/cnt (bf16) -> Ttile ----
    {
        const int lrow = lane >> 2;
        const int lq   = lane & 3;
        int n = n0 + lrow;
        if (n >= NN) n = NN - 1;
        const int cntn = row_start[n + 1] - row_start[n];
        const float inv  = (cntn > 0) ? (1.f / (float)cntn) : 1.f;
        if (lq == 0) addb_s[lrow] = (cntn > 0) ? 1.f : 0.f;
        const uint4* xr = (const uint4*)(xbf + (size_t)n * NF);
        const nfloat4* hr = (const nfloat4*)(H + (size_t)n * NH);
#pragma unroll
        for (int it = 0; it < 4; ++it) {
            const int g = lq + it * 4;
            *(uint4*)&Atile[lrow][g * 8] = xr[g];
            nfloat4 v0 = hr[g * 2], v1 = hr[g * 2 + 1];
            nfloat4 u0, u1;
            u0.x = v0.x * inv; u0.y = v0.y * inv; u0.z = v0.z * inv; u0.w = v0.w * inv;
            u1.x = v1.x * inv; u1.y = v1.y * inv; u1.z = v1.z * inv; u1.w = v1.w * inv;
            *(uint4*)&Ttile[lrow][g * 8] = __builtin_bit_cast(uint4, cvt8(u0, u1));
        }
    }
    lds_fence();   // staging writes -> frag/addb reads (wave-private)

    // ---- GEMM0: agg = Hm @ W1b + addb*b1b -> bf16 Atile[128..255] ----
    {
        bf16x8 ah[4];
#pragma unroll
        for (int ks = 0; ks < 4; ++ks)
            ah[ks] = load_frag(&Ttile[lm][ks * 32 + lq4 * 8]);
#pragma unroll
        for (int ct = 0; ct < 8; ++ct) {
            floatx4 acc = {0.f, 0.f, 0.f, 0.f};
            const unsigned short* wr = wp1b + (ct * 4 * 64 + lane) * 8;
#pragma unroll
            for (int ks = 0; ks < 4; ++ks) {
                bf16x8 b = load_frag(wr + ks * 512);
                acc = mfma16(ah[ks], b, acc);
            }
            const int c = ct * 16 + lm;
            const float bb = b1b[c];
#pragma unroll
            for (int i = 0; i < 4; ++i) {
                float av = acc[i] + addb_s[lq4 * 4 + i] * bb;
                Atile[lq4 * 4 + i][128 + c] = f2bf(av);
            }
        }
    }
    lds_fence();   // agg writes -> a1 reads (wave-private)

    bf16x8 a1[8];
#pragma unroll
    for (int ks = 0; ks < 8; ++ks)
        a1[ks] = load_frag(&Atile[lm][ks * 32 + lq4 * 8]);

    floatx4 acc1[8];
#pragma unroll
    for (int ct = 0; ct < 8; ++ct) {
        floatx4 acc = {0.f, 0.f, 0.f, 0.f};
        const unsigned short* wr = wp2a + (ct * 8 * 64 + lane) * 8;
#pragma unroll
        for (int ks = 0; ks < 8; ++ks) {
            bf16x8 b = load_frag(wr + ks * 512);
            acc = mfma16(a1[ks], b, acc);
        }
        acc1[ct] = acc;
    }

    float sum_[4] = {0, 0, 0, 0}, sq_[4] = {0, 0, 0, 0};
#pragma unroll
    for (int ct = 0; ct < 8; ++ct) {
        const float bb = b2a[ct * 16 + lm];
#pragma unroll
        for (int i = 0; i < 4; ++i) {
            float v = acc1[ct][i] + bb;
            v = fmaxf(v, 0.f);
            acc1[ct][i] = v;
            sum_[i] += v;
            sq_[i]  += v * v;
        }
    }
#pragma unroll
    for (int m = 1; m < 16; m <<= 1) {
#pragma unroll
        for (int i = 0; i < 4; ++i) {
            sum_[i] += __shfl_xor(sum_[i], m, 64);
            sq_[i]  += __shfl_xor(sq_[i],  m, 64);
        }
    }
    float mu[4], rs[4];
#pragma unroll
    for (int i = 0; i < 4; ++i) {
        mu[i] = sum_[i] * (1.f / NH);
        float var = sq_[i] * (1.f / NH) - mu[i] * mu[i];
        rs[i] = rsqrtf(var + LN_EPS);
    }
#pragma unroll
    for (int ct = 0; ct < 8; ++ct) {
        const int c = ct * 16 + lm;
        const float gg = g2[c], bb = be2[c];
#pragma unroll
        for (int i = 0; i < 4; ++i) {
            float nv = (acc1[ct][i] - mu[i]) * rs[i] * gg + bb;
            Ttile[lq4 * 4 + i][c] = f2bf(nv);
        }
    }
    lds_fence();   // LN writes -> a2 reads (wave-private)

    bf16x8 a2[4];
#pragma unroll
    for (int ks = 0; ks < 4; ++ks)
        a2[ks] = load_frag(&Ttile[lm][ks * 32 + lq4 * 8]);

#pragma unroll
    for (int ct = 0; ct < 8; ++ct) {
        floatx4 acc = {0.f, 0.f, 0.f, 0.f};
        const unsigned short* wr = wp2b + (ct * 4 * 64 + lane) * 8;
#pragma unroll
        for (int ks = 0; ks < 4; ++ks) {
            bf16x8 b = load_frag(wr + ks * 512);
            acc = mfma16(a2[ks], b, acc);
        }
        const int c = ct * 16 + lm;
        const float bb = b2b[c];
#pragma unroll
        for (int i = 0; i < 4; ++i) {
            int n = n0 + lq4 * 4 + i;
            if (n < NN) out[n * NT + c] = acc[i] + bb;
        }
    }
}

// ---------------------------------------------------------------------------
// Workspace layout (bytes):
//   [0,          5,120,000)  H (sums)  f32 [10000][128]
//   [5,120,000,  5,160,000)  hist      int [10000]
//   [5,160,000,  5,200,000)  cursor    int [10000]
//   [5,200,000,  5,240,064)  row_start int [10001] (padded)
//   [5,240,064,  7,800,064)  perm      int [640000]
//   [7,800,064,  7,865,600)  wp1a      bf16 frag-packed [64][64][8]
//   [7,865,600,  7,898,368)  wp1b      bf16 frag-packed [32][64][8]
//   [7,898,368,  7,963,904)  wp2a      bf16 frag-packed [64][64][8]
//   [7,963,904,  7,996,672)  wp2b      bf16 frag-packed [32][64][8]
//   [7,996,672, 10,556,672)  xbf       bf16 [10000][128]
// ---------------------------------------------------------------------------
extern "C" void kernel_launch(void* const* d_in, const int* in_sizes, int n_in,
                              void* d_out, int out_size, void* d_ws, size_t ws_size,
                              hipStream_t stream) {
    const float* x     = (const float*)d_in[0];
    const int*   eidx  = (const int*)d_in[1];
    const float* eattr = (const float*)d_in[2];
    const float* W1a = (const float*)d_in[3];
    const float* b1a = (const float*)d_in[4];
    const float* g1  = (const float*)d_in[5];
    const float* be1 = (const float*)d_in[6];
    const float* W1b = (const float*)d_in[7];
    const float* b1b = (const float*)d_in[8];
    const float* W2a = (const float*)d_in[9];
    const float* b2a = (const float*)d_in[10];
    const float* g2  = (const float*)d_in[11];
    const float* be2 = (const float*)d_in[12];
    const float* W2b = (const float*)d_in[13];
    const float* b2b = (const float*)d_in[14];

    char* ws = (char*)d_ws;
    float* H         = (float*)ws;
    int*   hist      = (int*)(ws + 5120000);
    int*   cursor    = (int*)(ws + 5160000);
    int*   row_start = (int*)(ws + 5200000);
    int*   perm      = (int*)(ws + 5240064);
    unsigned short* wp1a = (unsigned short*)(ws + 7800064);
    unsigned short* wp1b = (unsigned short*)(ws + 7865600);
    unsigned short* wp2a = (unsigned short*)(ws + 7898368);
    unsigned short* wp2b = (unsigned short*)(ws + 7963904);
    unsigned short* xbf  = (unsigned short*)(ws + 7996672);

    const int* erow = eidx;
    const int* ecol = eidx + NE;

    (void)hipMemsetAsync(ws, 0, 5160000, stream);   // zero H + hist
    prep_kernel<<<640, 256, 0, stream>>>(x, erow, W1a, W1b, W2a, W2b,
                                         wp1a, wp1b, wp2a, wp2b, xbf, hist);
    scan_kernel<<<1, 256, 0, stream>>>(hist, row_start, cursor);
    scatter_kernel<<<(NE + 255) / 256, 256, 0, stream>>>(erow, cursor, perm);
    edge_mlp_kernel<<<NE / 64, 256, 0, stream>>>(xbf, erow, ecol, eattr, perm,
                                                 wp1a, b1a, g1, be1, H);
    node_mlp_kernel<<<(NN + 15) / 16, 64, 0, stream>>>(xbf, H, row_start,
                                                       b1b, wp1b,
                                                       wp2a, b2a, g2, be2,
                                                       wp2b, b2b,
                                                       (float*)d_out);
}

// Round 9
// 663.826 us; speedup vs baseline: 3.0108x; 1.0355x over previous
//
#include <hip/hip_runtime.h>
#include <hip/hip_bf16.h>

#define NN 10000
#define NE 640000
#define NF 128
#define NH 128
#define NT 128
#define KA 256   // NF + NH
#define LN_EPS 1e-5f

typedef __bf16 bf16x8 __attribute__((ext_vector_type(8)));
typedef float floatx4 __attribute__((ext_vector_type(4)));
typedef float nfloat4 __attribute__((ext_vector_type(4)));

__device__ inline unsigned short f2bf(float f) {
    unsigned int u = __float_as_uint(f);
    u += 0x7FFFu + ((u >> 16) & 1u);   // round-to-nearest-even
    return (unsigned short)(u >> 16);
}

__device__ inline bf16x8 load_frag(const unsigned short* p) {
    uint4 u = *(const uint4*)p;
    return __builtin_bit_cast(bf16x8, u);
}

__device__ inline floatx4 mfma16(bf16x8 a, bf16x8 b, floatx4 c) {
    return __builtin_amdgcn_mfma_f32_16x16x32_bf16(a, b, c, 0, 0, 0);
}

// native casts -> v_cvt_pk_bf16_f32 (RTNE), 2 floats/instr
__device__ inline bf16x8 cvt8(nfloat4 v0, nfloat4 v1) {
    bf16x8 r;
    r[0] = (__bf16)v0.x; r[1] = (__bf16)v0.y; r[2] = (__bf16)v0.z; r[3] = (__bf16)v0.w;
    r[4] = (__bf16)v1.x; r[5] = (__bf16)v1.y; r[6] = (__bf16)v1.z; r[7] = (__bf16)v1.w;
    return r;
}

// wave-local LDS ordering fence; sched_barrier stops hipcc hoisting past it
__device__ inline void lds_fence() {
    asm volatile("s_waitcnt lgkmcnt(0)" ::: "memory");
    __builtin_amdgcn_sched_barrier(0);
}

// ---------------------------------------------------------------------------
// Prep (+ fused histogram): pack weights f32 [K][N] -> bf16 MFMA-fragment
// order, x -> bf16, and build the row histogram.
// Fragment f=(ct*nks+ks): 64 lanes x 8 elems contiguous (1KB). Lane l holds
// B[k = ks*32 + (l>>4)*8 + j][n = ct*16 + (l&15)].
// ---------------------------------------------------------------------------
__global__ __launch_bounds__(256) void prep_kernel(
    const float* __restrict__ x,
    const int* __restrict__ erow,
    const float* __restrict__ W1a, const float* __restrict__ W1b,
    const float* __restrict__ W2a, const float* __restrict__ W2b,
    unsigned short* __restrict__ wp1a, unsigned short* __restrict__ wp1b,
    unsigned short* __restrict__ wp2a, unsigned short* __restrict__ wp2b,
    unsigned short* __restrict__ xbf, int* __restrict__ hist)
{
    const int tid = blockIdx.x * 256 + threadIdx.x;
    const int nth = gridDim.x * 256;

    // histogram of target rows (fused: overlaps the streaming below)
    for (int e = tid; e < NE; e += nth)
        atomicAdd(&hist[erow[e]], 1);

    // x (f32 [10000][128]) -> xbf (bf16), 160000 x 16B
    const nfloat4* xs = (const nfloat4*)x;
    uint4* xd = (uint4*)xbf;
    for (int i = tid; i < 160000; i += nth)
        xd[i] = __builtin_bit_cast(uint4, cvt8(xs[2 * i], xs[2 * i + 1]));

    if (tid < 12288) {
        const float* src; unsigned short* dst; int t, nks;
        if (tid < 4096)       { src = W1a; dst = wp1a; t = tid;         nks = 8; }
        else if (tid < 6144)  { src = W1b; dst = wp1b; t = tid - 4096;  nks = 4; }
        else if (tid < 10240) { src = W2a; dst = wp2a; t = tid - 6144;  nks = 8; }
        else                  { src = W2b; dst = wp2b; t = tid - 10240; nks = 4; }
        const int f = t >> 6, l = t & 63;
        const int ct = f / nks, ks = f - ct * nks;
        const int n  = ct * 16 + (l & 15);
        const int k0 = ks * 32 + (l >> 4) * 8;
        unsigned short tmp[8];
#pragma unroll
        for (int j = 0; j < 8; ++j)
            tmp[j] = f2bf(src[(k0 + j) * 128 + n]);
        *(uint4*)&dst[t * 8] = *(const uint4*)tmp;
    }
}

// ---------------------------------------------------------------------------
// Counting sort by target row: scan -> scatter (+ fused xw GEMM).
// ---------------------------------------------------------------------------
__global__ __launch_bounds__(256) void scan_kernel(
    const int* __restrict__ hist, int* __restrict__ row_start,
    int* __restrict__ cursor)
{
    __shared__ int partials[256];
    const int t = threadIdx.x;
    const int base = t * 40;                  // 256*40 = 10240 >= NN
    int s = 0;
    for (int i = 0; i < 40; ++i) {
        int b = base + i;
        if (b < NN) s += hist[b];
    }
    partials[t] = s;
    __syncthreads();
    int pre = 0;
    for (int i = 0; i < t; ++i) pre += partials[i];
    int run = pre;
    for (int i = 0; i < 40; ++i) {
        int b = base + i;
        if (b < NN) {
            row_start[b] = run;
            cursor[b] = run;
            run += hist[b];
        }
    }
    if (t == 255) row_start[NN] = NE;
}

// scatter + fused xw: xw[n] = xbf[n] @ W1a[0:128,:] + b1a  (per-NODE hoist of
// the x-half of the edge GEMM1 -- x is reused by 64 edges on average).
// Blocks 0..624: wave 0 additionally computes xw for nodes [bid*16, bid*16+16).
__global__ __launch_bounds__(256) void scatter_kernel(
    const int* __restrict__ row, int* __restrict__ cursor,
    int* __restrict__ perm,
    const unsigned short* __restrict__ xbf,
    const unsigned short* __restrict__ wp1a, const float* __restrict__ b1a,
    float* __restrict__ xw)
{
    __shared__ unsigned short Xt[16][136];

    int e = blockIdx.x * 256 + threadIdx.x;
    if (e < NE) {
        int p = atomicAdd(&cursor[row[e]], 1);
        perm[p] = e;
    }

    if (blockIdx.x < 625 && threadIdx.x < 64) {
        const int lane = threadIdx.x;
        const int lm   = lane & 15;
        const int lq4  = lane >> 4;
        const int n0   = blockIdx.x * 16;
        {
            const int lrow = lane >> 2;
            const int lq   = lane & 3;
            const uint4* xr = (const uint4*)(xbf + (size_t)(n0 + lrow) * NF);
#pragma unroll
            for (int it = 0; it < 4; ++it) {
                const int g = lq + it * 4;
                *(uint4*)&Xt[lrow][g * 8] = xr[g];
            }
        }
        lds_fence();   // wave-private staging -> frag reads

        bf16x8 a[4];
#pragma unroll
        for (int ks = 0; ks < 4; ++ks)
            a[ks] = load_frag(&Xt[lm][ks * 32 + lq4 * 8]);

#pragma unroll
        for (int ct = 0; ct < 8; ++ct) {
            floatx4 acc = {0.f, 0.f, 0.f, 0.f};
            const unsigned short* wr = wp1a + ((ct * 8) * 64 + lane) * 8;
#pragma unroll
            for (int ks = 0; ks < 4; ++ks) {
                bf16x8 b = load_frag(wr + ks * 512);
                acc = mfma16(a[ks], b, acc);
            }
            const int c = ct * 16 + lm;
            const float bb = b1a[c];
#pragma unroll
            for (int i = 0; i < 4; ++i)
                xw[(size_t)(n0 + lq4 * 4 + i) * NH + c] = acc[i] + bb;
        }
    }
}

// ---------------------------------------------------------------------------
// Edge MLP "K128": x-half of GEMM1 hoisted per-node (xw). Per 64-edge tile:
// stage ONLY eattr (bf16, [64][136]) -> a1 (4 frags) -> GEMM1 K=128 with
// accumulator INITIALIZED from xw[col[e]] (bias folded in) -> ReLU/LN ->
// f32 h1 into accbuf (aliases dead Atile) -> ONE barrier -> segmented sum
// -> atomicAdd into H.  32 MFMA + 32KB weight-L2 per wave (was 64 + 64KB);
// staging halved. LDS 34KB -> 4 blocks/CU.
// ---------------------------------------------------------------------------
__global__ __launch_bounds__(256, 4) void edge_mlp_kernel(
    const float* __restrict__ xw,
    const int* __restrict__ erow, const int* __restrict__ ecol,
    const float* __restrict__ eattr,
    const int* __restrict__ perm,
    const unsigned short* __restrict__ wp1a,
    const float* __restrict__ g1, const float* __restrict__ be1,
    float* __restrict__ H)
{
    __shared__ __align__(16) float smem[64 * 132];   // 33792 B, aliased views
    __shared__ int rows_s[64];

    const int wave = threadIdx.x >> 6;
    const int lane = threadIdx.x & 63;
    const int lm   = lane & 15;
    const int lq4  = lane >> 4;
    const int e0   = blockIdx.x * 64;

    unsigned short* At = (unsigned short*)smem;      // [64][136] shorts view

    if (threadIdx.x < 64)
        rows_s[threadIdx.x] = erow[perm[e0 + threadIdx.x]];

    // ---- stage eattr (bf16) into own wave's rows ----
    {
        const int lrow = lane >> 2;          // 0..15: edge slot within wave
        const int lq   = lane & 3;
        const int e = perm[e0 + wave * 16 + lrow];
        const nfloat4* ar = (const nfloat4*)(eattr + (size_t)e * NH);
        unsigned short* Ar = At + (wave * 16 + lrow) * 136;
#pragma unroll
        for (int it = 0; it < 4; ++it) {
            const int g = lq + it * 4;       // 16B granule 0..15
            nfloat4 v0 = __builtin_nontemporal_load(ar + g * 2);
            nfloat4 v1 = __builtin_nontemporal_load(ar + g * 2 + 1);
            *(uint4*)&Ar[g * 8] = __builtin_bit_cast(uint4, cvt8(v0, v1));
        }
    }

    // ---- acc init = xw[col[e_r]] (x-half + b1a, hoisted per node) ----
    int scol_own = 0;
    if (lane < 16) scol_own = ecol[perm[e0 + wave * 16 + lane]];
    floatx4 acc1[8];
#pragma unroll
    for (int i = 0; i < 4; ++i) {
        const int sc = __shfl(scol_own, lq4 * 4 + i, 64);
        const float* xr = xw + (size_t)sc * NH + lm;
#pragma unroll
        for (int ct = 0; ct < 8; ++ct)
            acc1[ct][i] = xr[ct * 16];       // 64B-coalesced per lm-group
    }

    lds_fence();   // own-wave staging writes -> own-wave frag reads

    bf16x8 a1[4];
#pragma unroll
    for (int ks = 0; ks < 4; ++ks)
        a1[ks] = load_frag(&At[(wave * 16 + lm) * 136 + ks * 32 + lq4 * 8]);

    // ---- GEMM1 (eattr half): [16 x 128] @ [128 x 128], B = wp1a ks 4..7 ----
#pragma unroll
    for (int ct = 0; ct < 8; ++ct) {
        floatx4 acc = acc1[ct];
        const unsigned short* wr = wp1a + ((ct * 8 + 4) * 64 + lane) * 8;
#pragma unroll
        for (int ks = 0; ks < 4; ++ks) {
            bf16x8 b = load_frag(wr + ks * 512);
            acc = mfma16(a1[ks], b, acc);
        }
        acc1[ct] = acc;
    }

    // ---- ReLU + per-wave LayerNorm stats (bias already in xw) ----
    float sum_[4] = {0, 0, 0, 0}, sq_[4] = {0, 0, 0, 0};
#pragma unroll
    for (int ct = 0; ct < 8; ++ct) {
#pragma unroll
        for (int i = 0; i < 4; ++i) {
            float v = fmaxf(acc1[ct][i], 0.f);
            acc1[ct][i] = v;
            sum_[i] += v;
            sq_[i]  += v * v;
        }
    }
#pragma unroll
    for (int m = 1; m < 16; m <<= 1) {
#pragma unroll
        for (int i = 0; i < 4; ++i) {
            sum_[i] += __shfl_xor(sum_[i], m, 64);
            sq_[i]  += __shfl_xor(sq_[i],  m, 64);
        }
    }
    float mu[4], rs[4];
#pragma unroll
    for (int i = 0; i < 4; ++i) {
        mu[i] = sum_[i] * (1.f / NH);
        float var = sq_[i] * (1.f / NH) - mu[i] * mu[i];
        rs[i] = rsqrtf(var + LN_EPS);
    }

    // ---- LN apply -> f32 h1 into accbuf (aliases dead Atile; h1 stores
    // data-depend on a1-derived acc so write-after-read order holds) ----
#pragma unroll
    for (int ct = 0; ct < 8; ++ct) {
        const int c = ct * 16 + lm;
        const float gg = g1[c], bb = be1[c];
#pragma unroll
        for (int i = 0; i < 4; ++i) {
            const int r = wave * 16 + lq4 * 4 + i;
            smem[r * 132 + c] = (acc1[ct][i] - mu[i]) * rs[i] * gg + bb;
        }
    }
    __syncthreads();   // the ONE true cross-wave barrier

    // ---- segmented reduction over the block's 64 sorted edges -> H ----
    {
        const int t = threadIdx.x;
        const int cc = t & 127;
        const int jb = (t >> 7) * 32;
        float a = 0.f;
        int cur = rows_s[jb];
#pragma unroll 4
        for (int j = jb; j < jb + 32; ++j) {
            a += smem[j * 132 + cc];
            int nxt = (j + 1 < jb + 32) ? rows_s[j + 1] : -1;
            if (nxt != cur) {
                atomicAdd(&H[cur * NH + cc], a);
                a = 0.f;
                cur = nxt;
            }
        }
    }
}

// ---------------------------------------------------------------------------
// Node MLP, single-wave blocks (R8, validated): 64 threads = 16 nodes,
// grid 625. agg = (H[n]/cnt)@W1b + b1b (cnt>0) via linearity, then
// A = [x | agg] -> MLP2. Zero __syncthreads.
// ---------------------------------------------------------------------------
__global__ __launch_bounds__(64) void node_mlp_kernel(
    const unsigned short* __restrict__ xbf,
    const float* __restrict__ H, const int* __restrict__ row_start,
    const float* __restrict__ b1b, const unsigned short* __restrict__ wp1b,
    const unsigned short* __restrict__ wp2a, const float* __restrict__ b2a,
    const float* __restrict__ g2, const float* __restrict__ be2,
    const unsigned short* __restrict__ wp2b, const float* __restrict__ b2b,
    float* __restrict__ out)
{
    __shared__ unsigned short Atile[16][KA + 8];
    __shared__ unsigned short Ttile[16][NH + 8];   // Hm frags, later LN out
    __shared__ float addb_s[16];

    const int lane = threadIdx.x;        // 0..63, one wave
    const int lm   = lane & 15;
    const int lq4  = lane >> 4;
    const int n0   = blockIdx.x * 16;

    // ---- stage x -> Atile[0..127], Hm = H/cnt (bf16) -> Ttile ----
    {
        const int lrow = lane >> 2;
        const int lq   = lane & 3;
        int n = n0 + lrow;
        if (n >= NN) n = NN - 1;
        const int cntn = row_start[n + 1] - row_start[n];
        const float inv  = (cntn > 0) ? (1.f / (float)cntn) : 1.f;
        if (lq == 0) addb_s[lrow] = (cntn > 0) ? 1.f : 0.f;
        const uint4* xr = (const uint4*)(xbf + (size_t)n * NF);
        const nfloat4* hr = (const nfloat4*)(H + (size_t)n * NH);
#pragma unroll
        for (int it = 0; it < 4; ++it) {
            const int g = lq + it * 4;
            *(uint4*)&Atile[lrow][g * 8] = xr[g];
            nfloat4 v0 = hr[g * 2], v1 = hr[g * 2 + 1];
            nfloat4 u0, u1;
            u0.x = v0.x * inv; u0.y = v0.y * inv; u0.z = v0.z * inv; u0.w = v0.w * inv;
            u1.x = v1.x * inv; u1.y = v1.y * inv; u1.z = v1.z * inv; u1.w = v1.w * inv;
            *(uint4*)&Ttile[lrow][g * 8] = __builtin_bit_cast(uint4, cvt8(u0, u1));
        }
    }
    lds_fence();   // staging writes -> frag/addb reads (wave-private)

    // ---- GEMM0: agg = Hm @ W1b + addb*b1b -> bf16 Atile[128..255] ----
    {
        bf16x8 ah[4];
#pragma unroll
        for (int ks = 0; ks < 4; ++ks)
            ah[ks] = load_frag(&Ttile[lm][ks * 32 + lq4 * 8]);
#pragma unroll
        for (int ct = 0; ct < 8; ++ct) {
            floatx4 acc = {0.f, 0.f, 0.f, 0.f};
            const unsigned short* wr = wp1b + (ct * 4 * 64 + lane) * 8;
#pragma unroll
            for (int ks = 0; ks < 4; ++ks) {
                bf16x8 b = load_frag(wr + ks * 512);
                acc = mfma16(ah[ks], b, acc);
            }
            const int c = ct * 16 + lm;
            const float bb = b1b[c];
#pragma unroll
            for (int i = 0; i < 4; ++i) {
                float av = acc[i] + addb_s[lq4 * 4 + i] * bb;
                Atile[lq4 * 4 + i][128 + c] = f2bf(av);
            }
        }
    }
    lds_fence();   // agg writes -> a1 reads (wave-private)

    bf16x8 a1[8];
#pragma unroll
    for (int ks = 0; ks < 8; ++ks)
        a1[ks] = load_frag(&Atile[lm][ks * 32 + lq4 * 8]);

    floatx4 acc1[8];
#pragma unroll
    for (int ct = 0; ct < 8; ++ct) {
        floatx4 acc = {0.f, 0.f, 0.f, 0.f};
        const unsigned short* wr = wp2a + (ct * 8 * 64 + lane) * 8;
#pragma unroll
        for (int ks = 0; ks < 8; ++ks) {
            bf16x8 b = load_frag(wr + ks * 512);
            acc = mfma16(a1[ks], b, acc);
        }
        acc1[ct] = acc;
    }

    float sum_[4] = {0, 0, 0, 0}, sq_[4] = {0, 0, 0, 0};
#pragma unroll
    for (int ct = 0; ct < 8; ++ct) {
        const float bb = b2a[ct * 16 + lm];
#pragma unroll
        for (int i = 0; i < 4; ++i) {
            float v = acc1[ct][i] + bb;
            v = fmaxf(v, 0.f);
            acc1[ct][i] = v;
            sum_[i] += v;
            sq_[i]  += v * v;
        }
    }
#pragma unroll
    for (int m = 1; m < 16; m <<= 1) {
#pragma unroll
        for (int i = 0; i < 4; ++i) {
            sum_[i] += __shfl_xor(sum_[i], m, 64);
            sq_[i]  += __shfl_xor(sq_[i],  m, 64);
        }
    }
    float mu[4], rs[4];
#pragma unroll
    for (int i = 0; i < 4; ++i) {
        mu[i] = sum_[i] * (1.f / NH);
        float var = sq_[i] * (1.f / NH) - mu[i] * mu[i];
        rs[i] = rsqrtf(var + LN_EPS);
    }
#pragma unroll
    for (int ct = 0; ct < 8; ++ct) {
        const int c = ct * 16 + lm;
        const float gg = g2[c], bb = be2[c];
#pragma unroll
        for (int i = 0; i < 4; ++i) {
            float nv = (acc1[ct][i] - mu[i]) * rs[i] * gg + bb;
            Ttile[lq4 * 4 + i][c] = f2bf(nv);
        }
    }
    lds_fence();   // LN writes -> a2 reads (wave-private)

    bf16x8 a2[4];
#pragma unroll
    for (int ks = 0; ks < 4; ++ks)
        a2[ks] = load_frag(&Ttile[lm][ks * 32 + lq4 * 8]);

#pragma unroll
    for (int ct = 0; ct < 8; ++ct) {
        floatx4 acc = {0.f, 0.f, 0.f, 0.f};
        const unsigned short* wr = wp2b + (ct * 4 * 64 + lane) * 8;
#pragma unroll
        for (int ks = 0; ks < 4; ++ks) {
            bf16x8 b = load_frag(wr + ks * 512);
            acc = mfma16(a2[ks], b, acc);
        }
        const int c = ct * 16 + lm;
        const float bb = b2b[c];
#pragma unroll
        for (int i = 0; i < 4; ++i) {
            int n = n0 + lq4 * 4 + i;
            if (n < NN) out[n * NT + c] = acc[i] + bb;
        }
    }
}

// ---------------------------------------------------------------------------
// Workspace layout (bytes):
//   [0,          5,120,000)  H (sums)  f32 [10000][128]
//   [5,120,000,  5,160,000)  hist      int [10000]
//   [5,160,000,  5,200,000)  cursor    int [10000]
//   [5,200,000,  5,240,064)  row_start int [10001] (padded)
//   [5,240,064,  7,800,064)  perm      int [640000]
//   [7,800,064,  7,865,600)  wp1a      bf16 frag-packed [64][64][8]
//   [7,865,600,  7,898,368)  wp1b      bf16 frag-packed [32][64][8]
//   [7,898,368,  7,963,904)  wp2a      bf16 frag-packed [64][64][8]
//   [7,963,904,  7,996,672)  wp2b      bf16 frag-packed [32][64][8]
//   [7,996,672, 10,556,672)  xbf       bf16 [10000][128]
//   [10,556,672, 15,676,672) xw        f32 [10000][128]  (x@W1a_top + b1a)
// ---------------------------------------------------------------------------
extern "C" void kernel_launch(void* const* d_in, const int* in_sizes, int n_in,
                              void* d_out, int out_size, void* d_ws, size_t ws_size,
                              hipStream_t stream) {
    const float* x     = (const float*)d_in[0];
    const int*   eidx  = (const int*)d_in[1];
    const float* eattr = (const float*)d_in[2];
    const float* W1a = (const float*)d_in[3];
    const float* b1a = (const float*)d_in[4];
    const float* g1  = (const float*)d_in[5];
    const float* be1 = (const float*)d_in[6];
    const float* W1b = (const float*)d_in[7];
    const float* b1b = (const float*)d_in[8];
    const float* W2a = (const float*)d_in[9];
    const float* b2a = (const float*)d_in[10];
    const float* g2  = (const float*)d_in[11];
    const float* be2 = (const float*)d_in[12];
    const float* W2b = (const float*)d_in[13];
    const float* b2b = (const float*)d_in[14];

    char* ws = (char*)d_ws;
    float* H         = (float*)ws;
    int*   hist      = (int*)(ws + 5120000);
    int*   cursor    = (int*)(ws + 5160000);
    int*   row_start = (int*)(ws + 5200000);
    int*   perm      = (int*)(ws + 5240064);
    unsigned short* wp1a = (unsigned short*)(ws + 7800064);
    unsigned short* wp1b = (unsigned short*)(ws + 7865600);
    unsigned short* wp2a = (unsigned short*)(ws + 7898368);
    unsigned short* wp2b = (unsigned short*)(ws + 7963904);
    unsigned short* xbf  = (unsigned short*)(ws + 7996672);
    float* xw        = (float*)(ws + 10556672);

    const int* erow = eidx;
    const int* ecol = eidx + NE;

    (void)hipMemsetAsync(ws, 0, 5160000, stream);   // zero H + hist
    prep_kernel<<<640, 256, 0, stream>>>(x, erow, W1a, W1b, W2a, W2b,
                                         wp1a, wp1b, wp2a, wp2b, xbf, hist);
    scan_kernel<<<1, 256, 0, stream>>>(hist, row_start, cursor);
    scatter_kernel<<<(NE + 255) / 256, 256, 0, stream>>>(erow, cursor, perm,
                                                         xbf, wp1a, b1a, xw);
    edge_mlp_kernel<<<NE / 64, 256, 0, stream>>>(xw, erow, ecol, eattr, perm,
                                                 wp1a, g1, be1, H);
    node_mlp_kernel<<<(NN + 15) / 16, 64, 0, stream>>>(xbf, H, row_start,
                                                       b1b, wp1b,
                                                       wp2a, b2a, g2, be2,
                                                       wp2b, b2b,
                                                       (float*)d_out);
}

// Round 10
// 655.332 us; speedup vs baseline: 3.0498x; 1.0130x over previous
//
#include <hip/hip_runtime.h>
#include <hip/hip_bf16.h>

#define NN 10000
#define NE 640000
#define NF 128
#define NH 128
#define NT 128
#define KA 256   // NF + NH
#define LN_EPS 1e-5f

typedef __bf16 bf16x8 __attribute__((ext_vector_type(8)));
typedef float floatx4 __attribute__((ext_vector_type(4)));
typedef float nfloat4 __attribute__((ext_vector_type(4)));

__device__ inline unsigned short f2bf(float f) {
    unsigned int u = __float_as_uint(f);
    u += 0x7FFFu + ((u >> 16) & 1u);   // round-to-nearest-even
    return (unsigned short)(u >> 16);
}

__device__ inline bf16x8 load_frag(const unsigned short* p) {
    uint4 u = *(const uint4*)p;
    return __builtin_bit_cast(bf16x8, u);
}

__device__ inline floatx4 mfma16(bf16x8 a, bf16x8 b, floatx4 c) {
    return __builtin_amdgcn_mfma_f32_16x16x32_bf16(a, b, c, 0, 0, 0);
}

// native casts -> v_cvt_pk_bf16_f32 (RTNE), 2 floats/instr
__device__ inline bf16x8 cvt8(nfloat4 v0, nfloat4 v1) {
    bf16x8 r;
    r[0] = (__bf16)v0.x; r[1] = (__bf16)v0.y; r[2] = (__bf16)v0.z; r[3] = (__bf16)v0.w;
    r[4] = (__bf16)v1.x; r[5] = (__bf16)v1.y; r[6] = (__bf16)v1.z; r[7] = (__bf16)v1.w;
    return r;
}

// wave-local LDS ordering fence; sched_barrier stops hipcc hoisting past it
__device__ inline void lds_fence() {
    asm volatile("s_waitcnt lgkmcnt(0)" ::: "memory");
    __builtin_amdgcn_sched_barrier(0);
}

// guaranteed-native device-scope f32 atomic add (no CAS fallback)
__device__ inline void atomic_add_f32(float* p, float v) {
    __hip_atomic_fetch_add(p, v, __ATOMIC_RELAXED, __HIP_MEMORY_SCOPE_AGENT);
}

// ---------------------------------------------------------------------------
// Prep (+ fused histogram): pack weights f32 [K][N] -> bf16 MFMA-fragment
// order, x -> bf16, and build the row histogram.
// Fragment f=(ct*nks+ks): 64 lanes x 8 elems contiguous (1KB). Lane l holds
// B[k = ks*32 + (l>>4)*8 + j][n = ct*16 + (l&15)].
// ---------------------------------------------------------------------------
__global__ __launch_bounds__(256) void prep_kernel(
    const float* __restrict__ x,
    const int* __restrict__ erow,
    const float* __restrict__ W1a, const float* __restrict__ W1b,
    const float* __restrict__ W2a, const float* __restrict__ W2b,
    unsigned short* __restrict__ wp1a, unsigned short* __restrict__ wp1b,
    unsigned short* __restrict__ wp2a, unsigned short* __restrict__ wp2b,
    unsigned short* __restrict__ xbf, int* __restrict__ hist)
{
    const int tid = blockIdx.x * 256 + threadIdx.x;
    const int nth = gridDim.x * 256;

    // histogram of target rows (fused: overlaps the streaming below)
    for (int e = tid; e < NE; e += nth)
        atomicAdd(&hist[erow[e]], 1);

    // x (f32 [10000][128]) -> xbf (bf16), 160000 x 16B
    const nfloat4* xs = (const nfloat4*)x;
    uint4* xd = (uint4*)xbf;
    for (int i = tid; i < 160000; i += nth)
        xd[i] = __builtin_bit_cast(uint4, cvt8(xs[2 * i], xs[2 * i + 1]));

    if (tid < 12288) {
        const float* src; unsigned short* dst; int t, nks;
        if (tid < 4096)       { src = W1a; dst = wp1a; t = tid;         nks = 8; }
        else if (tid < 6144)  { src = W1b; dst = wp1b; t = tid - 4096;  nks = 4; }
        else if (tid < 10240) { src = W2a; dst = wp2a; t = tid - 6144;  nks = 8; }
        else                  { src = W2b; dst = wp2b; t = tid - 10240; nks = 4; }
        const int f = t >> 6, l = t & 63;
        const int ct = f / nks, ks = f - ct * nks;
        const int n  = ct * 16 + (l & 15);
        const int k0 = ks * 32 + (l >> 4) * 8;
        unsigned short tmp[8];
#pragma unroll
        for (int j = 0; j < 8; ++j)
            tmp[j] = f2bf(src[(k0 + j) * 128 + n]);
        *(uint4*)&dst[t * 8] = *(const uint4*)tmp;
    }
}

// ---------------------------------------------------------------------------
// Counting sort by target row: scan -> scatter (+ fused xw GEMM).
// ---------------------------------------------------------------------------
__global__ __launch_bounds__(256) void scan_kernel(
    const int* __restrict__ hist, int* __restrict__ row_start,
    int* __restrict__ cursor)
{
    __shared__ int partials[256];
    const int t = threadIdx.x;
    const int base = t * 40;                  // 256*40 = 10240 >= NN
    int s = 0;
    for (int i = 0; i < 40; ++i) {
        int b = base + i;
        if (b < NN) s += hist[b];
    }
    partials[t] = s;
    __syncthreads();
    int pre = 0;
    for (int i = 0; i < t; ++i) pre += partials[i];
    int run = pre;
    for (int i = 0; i < 40; ++i) {
        int b = base + i;
        if (b < NN) {
            row_start[b] = run;
            cursor[b] = run;
            run += hist[b];
        }
    }
    if (t == 255) row_start[NN] = NE;
}

// scatter + fused xw: xw[n] = xbf[n] @ W1a[0:128,:] + b1a  (per-NODE hoist of
// the x-half of the edge GEMM1 -- x is reused by 64 edges on average).
// Blocks 0..624: wave 0 additionally computes xw for nodes [bid*16, bid*16+16).
__global__ __launch_bounds__(256) void scatter_kernel(
    const int* __restrict__ row, int* __restrict__ cursor,
    int* __restrict__ perm,
    const unsigned short* __restrict__ xbf,
    const unsigned short* __restrict__ wp1a, const float* __restrict__ b1a,
    float* __restrict__ xw)
{
    __shared__ unsigned short Xt[16][136];

    int e = blockIdx.x * 256 + threadIdx.x;
    if (e < NE) {
        int p = atomicAdd(&cursor[row[e]], 1);
        perm[p] = e;
    }

    if (blockIdx.x < 625 && threadIdx.x < 64) {
        const int lane = threadIdx.x;
        const int lm   = lane & 15;
        const int lq4  = lane >> 4;
        const int n0   = blockIdx.x * 16;
        {
            const int lrow = lane >> 2;
            const int lq   = lane & 3;
            const uint4* xr = (const uint4*)(xbf + (size_t)(n0 + lrow) * NF);
#pragma unroll
            for (int it = 0; it < 4; ++it) {
                const int g = lq + it * 4;
                *(uint4*)&Xt[lrow][g * 8] = xr[g];
            }
        }
        lds_fence();   // wave-private staging -> frag reads

        bf16x8 a[4];
#pragma unroll
        for (int ks = 0; ks < 4; ++ks)
            a[ks] = load_frag(&Xt[lm][ks * 32 + lq4 * 8]);

#pragma unroll
        for (int ct = 0; ct < 8; ++ct) {
            floatx4 acc = {0.f, 0.f, 0.f, 0.f};
            const unsigned short* wr = wp1a + ((ct * 8) * 64 + lane) * 8;
#pragma unroll
            for (int ks = 0; ks < 4; ++ks) {
                bf16x8 b = load_frag(wr + ks * 512);
                acc = mfma16(a[ks], b, acc);
            }
            const int c = ct * 16 + lm;
            const float bb = b1a[c];
#pragma unroll
            for (int i = 0; i < 4; ++i)
                xw[(size_t)(n0 + lq4 * 4 + i) * NH + c] = acc[i] + bb;
        }
    }
}

// ---------------------------------------------------------------------------
// Edge MLP "K128" (R9, validated) + R10 polish:
//  - xw index chain (perm->ecol) issued FIRST so its ~1000cy L2/L3 latency
//    overlaps the eattr HBM staging chain instead of following it.
//  - LN apply stores (v-mu)*rs only; gamma/beta hoisted to the node kernel
//    by linearity: sum(g*(v-mu)*rs + be) = g*sum((v-mu)*rs) + cnt*be.
//  - guaranteed-native f32 atomics into H.
// LDS 34KB -> 4 blocks/CU; one true barrier per block.
// ---------------------------------------------------------------------------
__global__ __launch_bounds__(256, 4) void edge_mlp_kernel(
    const float* __restrict__ xw,
    const int* __restrict__ erow, const int* __restrict__ ecol,
    const float* __restrict__ eattr,
    const int* __restrict__ perm,
    const unsigned short* __restrict__ wp1a,
    float* __restrict__ H)
{
    __shared__ __align__(16) float smem[64 * 132];   // 33792 B, aliased views
    __shared__ int rows_s[64];

    const int wave = threadIdx.x >> 6;
    const int lane = threadIdx.x & 63;
    const int lm   = lane & 15;
    const int lq4  = lane >> 4;
    const int e0   = blockIdx.x * 64;

    unsigned short* At = (unsigned short*)smem;      // [64][136] shorts view

    // ---- earliest: 2-hop index chain for the xw gather ----
    int scol_own = 0;
    if (lane < 16) scol_own = ecol[perm[e0 + wave * 16 + lane]];

    if (threadIdx.x < 64)
        rows_s[threadIdx.x] = erow[perm[e0 + threadIdx.x]];

    // ---- stage eattr (bf16) into own wave's rows ----
    {
        const int lrow = lane >> 2;          // 0..15: edge slot within wave
        const int lq   = lane & 3;
        const int e = perm[e0 + wave * 16 + lrow];
        const nfloat4* ar = (const nfloat4*)(eattr + (size_t)e * NH);
        unsigned short* Ar = At + (wave * 16 + lrow) * 136;
#pragma unroll
        for (int it = 0; it < 4; ++it) {
            const int g = lq + it * 4;       // 16B granule 0..15
            nfloat4 v0 = __builtin_nontemporal_load(ar + g * 2);
            nfloat4 v1 = __builtin_nontemporal_load(ar + g * 2 + 1);
            *(uint4*)&Ar[g * 8] = __builtin_bit_cast(uint4, cvt8(v0, v1));
        }
    }

    // ---- acc init = xw[col[e_r]] (x-half + b1a, hoisted per node) ----
    floatx4 acc1[8];
#pragma unroll
    for (int i = 0; i < 4; ++i) {
        const int sc = __shfl(scol_own, lq4 * 4 + i, 64);
        const float* xr = xw + (size_t)sc * NH + lm;
#pragma unroll
        for (int ct = 0; ct < 8; ++ct)
            acc1[ct][i] = xr[ct * 16];       // 64B-coalesced per lm-group
    }

    lds_fence();   // own-wave staging writes -> own-wave frag reads

    bf16x8 a1[4];
#pragma unroll
    for (int ks = 0; ks < 4; ++ks)
        a1[ks] = load_frag(&At[(wave * 16 + lm) * 136 + ks * 32 + lq4 * 8]);

    // ---- GEMM1 (eattr half): [16 x 128] @ [128 x 128], B = wp1a ks 4..7 ----
#pragma unroll
    for (int ct = 0; ct < 8; ++ct) {
        floatx4 acc = acc1[ct];
        const unsigned short* wr = wp1a + ((ct * 8 + 4) * 64 + lane) * 8;
#pragma unroll
        for (int ks = 0; ks < 4; ++ks) {
            bf16x8 b = load_frag(wr + ks * 512);
            acc = mfma16(a1[ks], b, acc);
        }
        acc1[ct] = acc;
    }

    // ---- ReLU + per-wave LayerNorm stats (bias already in xw) ----
    float sum_[4] = {0, 0, 0, 0}, sq_[4] = {0, 0, 0, 0};
#pragma unroll
    for (int ct = 0; ct < 8; ++ct) {
#pragma unroll
        for (int i = 0; i < 4; ++i) {
            float v = fmaxf(acc1[ct][i], 0.f);
            acc1[ct][i] = v;
            sum_[i] += v;
            sq_[i]  += v * v;
        }
    }
#pragma unroll
    for (int m = 1; m < 16; m <<= 1) {
#pragma unroll
        for (int i = 0; i < 4; ++i) {
            sum_[i] += __shfl_xor(sum_[i], m, 64);
            sq_[i]  += __shfl_xor(sq_[i],  m, 64);
        }
    }
    float mu[4], rs[4];
#pragma unroll
    for (int i = 0; i < 4; ++i) {
        mu[i] = sum_[i] * (1.f / NH);
        float var = sq_[i] * (1.f / NH) - mu[i] * mu[i];
        rs[i] = rsqrtf(var + LN_EPS);
    }

    // ---- normalized (no gamma/beta: hoisted to node) -> f32 accbuf ----
#pragma unroll
    for (int ct = 0; ct < 8; ++ct) {
        const int c = ct * 16 + lm;
#pragma unroll
        for (int i = 0; i < 4; ++i) {
            const int r = wave * 16 + lq4 * 4 + i;
            smem[r * 132 + c] = (acc1[ct][i] - mu[i]) * rs[i];
        }
    }
    __syncthreads();   // the ONE true cross-wave barrier

    // ---- segmented reduction over the block's 64 sorted edges -> H ----
    {
        const int t = threadIdx.x;
        const int cc = t & 127;
        const int jb = (t >> 7) * 32;
        float a = 0.f;
        int cur = rows_s[jb];
#pragma unroll 4
        for (int j = jb; j < jb + 32; ++j) {
            a += smem[j * 132 + cc];
            int nxt = (j + 1 < jb + 32) ? rows_s[j + 1] : -1;
            if (nxt != cur) {
                atomic_add_f32(&H[cur * NH + cc], a);
                a = 0.f;
                cur = nxt;
            }
        }
    }
}

// ---------------------------------------------------------------------------
// Node MLP, single-wave blocks (R8, validated): 64 threads = 16 nodes,
// grid 625. Hm = g1*(H[n]/cnt) + be1 (cnt>0, LN affine hoisted from edge),
// agg = Hm@W1b + b1b (cnt>0) via linearity, then A = [x | agg] -> MLP2.
// Zero __syncthreads.
// ---------------------------------------------------------------------------
__global__ __launch_bounds__(64) void node_mlp_kernel(
    const unsigned short* __restrict__ xbf,
    const float* __restrict__ H, const int* __restrict__ row_start,
    const float* __restrict__ g1, const float* __restrict__ be1,
    const float* __restrict__ b1b, const unsigned short* __restrict__ wp1b,
    const unsigned short* __restrict__ wp2a, const float* __restrict__ b2a,
    const float* __restrict__ g2, const float* __restrict__ be2,
    const unsigned short* __restrict__ wp2b, const float* __restrict__ b2b,
    float* __restrict__ out)
{
    __shared__ unsigned short Atile[16][KA + 8];
    __shared__ unsigned short Ttile[16][NH + 8];   // Hm frags, later LN out
    __shared__ float addb_s[16];

    const int lane = threadIdx.x;        // 0..63, one wave
    const int lm   = lane & 15;
    const int lq4  = lane >> 4;
    const int n0   = blockIdx.x * 16;

    // ---- stage x -> Atile[0..127], Hm = g1*(H/cnt) + addb*be1 -> Ttile ----
    {
        const int lrow = lane >> 2;
        const int lq   = lane & 3;
        int n = n0 + lrow;
        if (n >= NN) n = NN - 1;
        const int cntn = row_start[n + 1] - row_start[n];
        const float inv  = (cntn > 0) ? (1.f / (float)cntn) : 1.f;
        const float addb = (cntn > 0) ? 1.f : 0.f;
        if (lq == 0) addb_s[lrow] = addb;
        const uint4* xr = (const uint4*)(xbf + (size_t)n * NF);
        const nfloat4* hr = (const nfloat4*)(H + (size_t)n * NH);
        const nfloat4* gr = (const nfloat4*)g1;
        const nfloat4* br = (const nfloat4*)be1;
#pragma unroll
        for (int it = 0; it < 4; ++it) {
            const int g = lq + it * 4;
            *(uint4*)&Atile[lrow][g * 8] = xr[g];
            nfloat4 v0 = hr[g * 2], v1 = hr[g * 2 + 1];
            nfloat4 g0 = gr[g * 2], g1v = gr[g * 2 + 1];
            nfloat4 b0 = br[g * 2], b1v = br[g * 2 + 1];
            nfloat4 u0, u1;
            u0.x = v0.x * inv * g0.x  + addb * b0.x;
            u0.y = v0.y * inv * g0.y  + addb * b0.y;
            u0.z = v0.z * inv * g0.z  + addb * b0.z;
            u0.w = v0.w * inv * g0.w  + addb * b0.w;
            u1.x = v1.x * inv * g1v.x + addb * b1v.x;
            u1.y = v1.y * inv * g1v.y + addb * b1v.y;
            u1.z = v1.z * inv * g1v.z + addb * b1v.z;
            u1.w = v1.w * inv * g1v.w + addb * b1v.w;
            *(uint4*)&Ttile[lrow][g * 8] = __builtin_bit_cast(uint4, cvt8(u0, u1));
        }
    }
    lds_fence();   // staging writes -> frag/addb reads (wave-private)

    // ---- GEMM0: agg = Hm @ W1b + addb*b1b -> bf16 Atile[128..255] ----
    {
        bf16x8 ah[4];
#pragma unroll
        for (int ks = 0; ks < 4; ++ks)
            ah[ks] = load_frag(&Ttile[lm][ks * 32 + lq4 * 8]);
#pragma unroll
        for (int ct = 0; ct < 8; ++ct) {
            floatx4 acc = {0.f, 0.f, 0.f, 0.f};
            const unsigned short* wr = wp1b + (ct * 4 * 64 + lane) * 8;
#pragma unroll
            for (int ks = 0; ks < 4; ++ks) {
                bf16x8 b = load_frag(wr + ks * 512);
                acc = mfma16(ah[ks], b, acc);
            }
            const int c = ct * 16 + lm;
            const float bb = b1b[c];
#pragma unroll
            for (int i = 0; i < 4; ++i) {
                float av = acc[i] + addb_s[lq4 * 4 + i] * bb;
                Atile[lq4 * 4 + i][128 + c] = f2bf(av);
            }
        }
    }
    lds_fence();   // agg writes -> a1 reads (wave-private)

    bf16x8 a1[8];
#pragma unroll
    for (int ks = 0; ks < 8; ++ks)
        a1[ks] = load_frag(&Atile[lm][ks * 32 + lq4 * 8]);

    floatx4 acc1[8];
#pragma unroll
    for (int ct = 0; ct < 8; ++ct) {
        floatx4 acc = {0.f, 0.f, 0.f, 0.f};
        const unsigned short* wr = wp2a + (ct * 8 * 64 + lane) * 8;
#pragma unroll
        for (int ks = 0; ks < 8; ++ks) {
            bf16x8 b = load_frag(wr + ks * 512);
            acc = mfma16(a1[ks], b, acc);
        }
        acc1[ct] = acc;
    }

    float sum_[4] = {0, 0, 0, 0}, sq_[4] = {0, 0, 0, 0};
#pragma unroll
    for (int ct = 0; ct < 8; ++ct) {
        const float bb = b2a[ct * 16 + lm];
#pragma unroll
        for (int i = 0; i < 4; ++i) {
            float v = acc1[ct][i] + bb;
            v = fmaxf(v, 0.f);
            acc1[ct][i] = v;
            sum_[i] += v;
            sq_[i]  += v * v;
        }
    }
#pragma unroll
    for (int m = 1; m < 16; m <<= 1) {
#pragma unroll
        for (int i = 0; i < 4; ++i) {
            sum_[i] += __shfl_xor(sum_[i], m, 64);
            sq_[i]  += __shfl_xor(sq_[i],  m, 64);
        }
    }
    float mu[4], rs[4];
#pragma unroll
    for (int i = 0; i < 4; ++i) {
        mu[i] = sum_[i] * (1.f / NH);
        float var = sq_[i] * (1.f / NH) - mu[i] * mu[i];
        rs[i] = rsqrtf(var + LN_EPS);
    }
#pragma unroll
    for (int ct = 0; ct < 8; ++ct) {
        const int c = ct * 16 + lm;
        const float gg = g2[c], bb = be2[c];
#pragma unroll
        for (int i = 0; i < 4; ++i) {
            float nv = (acc1[ct][i] - mu[i]) * rs[i] * gg + bb;
            Ttile[lq4 * 4 + i][c] = f2bf(nv);
        }
    }
    lds_fence();   // LN writes -> a2 reads (wave-private)

    bf16x8 a2[4];
#pragma unroll
    for (int ks = 0; ks < 4; ++ks)
        a2[ks] = load_frag(&Ttile[lm][ks * 32 + lq4 * 8]);

#pragma unroll
    for (int ct = 0; ct < 8; ++ct) {
        floatx4 acc = {0.f, 0.f, 0.f, 0.f};
        const unsigned short* wr = wp2b + (ct * 4 * 64 + lane) * 8;
#pragma unroll
        for (int ks = 0; ks < 4; ++ks) {
            bf16x8 b = load_frag(wr + ks * 512);
            acc = mfma16(a2[ks], b, acc);
        }
        const int c = ct * 16 + lm;
        const float bb = b2b[c];
#pragma unroll
        for (int i = 0; i < 4; ++i) {
            int n = n0 + lq4 * 4 + i;
            if (n < NN) out[n * NT + c] = acc[i] + bb;
        }
    }
}

// ---------------------------------------------------------------------------
// Workspace layout (bytes):
//   [0,          5,120,000)  H (sums)  f32 [10000][128]
//   [5,120,000,  5,160,000)  hist      int [10000]
//   [5,160,000,  5,200,000)  cursor    int [10000]
//   [5,200,000,  5,240,064)  row_start int [10001] (padded)
//   [5,240,064,  7,800,064)  perm      int [640000]
//   [7,800,064,  7,865,600)  wp1a      bf16 frag-packed [64][64][8]
//   [7,865,600,  7,898,368)  wp1b      bf16 frag-packed [32][64][8]
//   [7,898,368,  7,963,904)  wp2a      bf16 frag-packed [64][64][8]
//   [7,963,904,  7,996,672)  wp2b      bf16 frag-packed [32][64][8]
//   [7,996,672, 10,556,672)  xbf       bf16 [10000][128]
//   [10,556,672, 15,676,672) xw        f32 [10000][128]  (x@W1a_top + b1a)
// ---------------------------------------------------------------------------
extern "C" void kernel_launch(void* const* d_in, const int* in_sizes, int n_in,
                              void* d_out, int out_size, void* d_ws, size_t ws_size,
                              hipStream_t stream) {
    const float* x     = (const float*)d_in[0];
    const int*   eidx  = (const int*)d_in[1];
    const float* eattr = (const float*)d_in[2];
    const float* W1a = (const float*)d_in[3];
    const float* b1a = (const float*)d_in[4];
    const float* g1  = (const float*)d_in[5];
    const float* be1 = (const float*)d_in[6];
    const float* W1b = (const float*)d_in[7];
    const float* b1b = (const float*)d_in[8];
    const float* W2a = (const float*)d_in[9];
    const float* b2a = (const float*)d_in[10];
    const float* g2  = (const float*)d_in[11];
    const float* be2 = (const float*)d_in[12];
    const float* W2b = (const float*)d_in[13];
    const float* b2b = (const float*)d_in[14];

    char* ws = (char*)d_ws;
    float* H         = (float*)ws;
    int*   hist      = (int*)(ws + 5120000);
    int*   cursor    = (int*)(ws + 5160000);
    int*   row_start = (int*)(ws + 5200000);
    int*   perm      = (int*)(ws + 5240064);
    unsigned short* wp1a = (unsigned short*)(ws + 7800064);
    unsigned short* wp1b = (unsigned short*)(ws + 7865600);
    unsigned short* wp2a = (unsigned short*)(ws + 7898368);
    unsigned short* wp2b = (unsigned short*)(ws + 7963904);
    unsigned short* xbf  = (unsigned short*)(ws + 7996672);
    float* xw        = (float*)(ws + 10556672);

    const int* erow = eidx;
    const int* ecol = eidx + NE;

    (void)hipMemsetAsync(ws, 0, 5160000, stream);   // zero H + hist
    prep_kernel<<<640, 256, 0, stream>>>(x, erow, W1a, W1b, W2a, W2b,
                                         wp1a, wp1b, wp2a, wp2b, xbf, hist);
    scan_kernel<<<1, 256, 0, stream>>>(hist, row_start, cursor);
    scatter_kernel<<<(NE + 255) / 256, 256, 0, stream>>>(erow, cursor, perm,
                                                         xbf, wp1a, b1a, xw);
    edge_mlp_kernel<<<NE / 64, 256, 0, stream>>>(xw, erow, ecol, eattr, perm,
                                                 wp1a, H);
    node_mlp_kernel<<<(NN + 15) / 16, 64, 0, stream>>>(xbf, H, row_start,
                                                       g1, be1, b1b, wp1b,
                                                       wp2a, b2a, g2, be2,
                                                       wp2b, b2b,
                                                       (float*)d_out);
}